// Round 1
// baseline (683.332 us; speedup 1.0000x reference)
//
#include <hip/hip_runtime.h>

// LLayer co-attention, all-f32 baseline.
// Pipeline: pad weights -> CW=comments@Wl (NN) -> L=tanh(CW@content^T) (NT)
//        -> Sc2=Ws2@content^T, Cc2=Wc2@comments^T (NT, K-dim padded 80->128)
//        -> zs = whs . tanh(Sc2 + Cc2@L)   (NN GEMM + fused reduce epilogue)
//        -> zc = whc . tanh(Cc2 + Sc2@L^T) (NT GEMM + fused reduce epilogue)
//        -> softmax + pooling -> out [128, 512]

#define TILE 128
#define BKC 16

__device__ __forceinline__ float fast_tanh(float x) {
  float ax = fabsf(x);
  float e = __expf(2.0f * ax);          // inf for large ax -> r = 1
  float r = 1.0f - 2.0f / (e + 1.0f);
  return copysignf(r, x);
}

// C[M,N] = epi(A[M,K] * B + biasterm). BT=1: B is [N][K] (NT). BT=0: B is [K][N] (NN).
// EPI: 0 = store, 1 = tanh+store, 2 = z[n] = sum_m wh[m]*tanh(acc+bias[m][n]) (no C store)
template<int BT, int EPI>
__global__ __launch_bounds__(256) void gemm128(
    const float* __restrict__ A, int lda, long long sA,
    const float* __restrict__ B, int ldb, long long sB,
    float* __restrict__ C, int ldc, long long sC,
    const float* __restrict__ bias, int ldbias, long long sBias,
    const float* __restrict__ wh,
    float* __restrict__ zout, int sZ,
    int Kd)
{
  __shared__ float As[BKC][TILE + 4];   // [k][m]
  __shared__ float Bs[BKC][TILE + 4];   // [k][n]
  const int b  = blockIdx.z;
  const int m0 = blockIdx.y * TILE;
  const int n0 = blockIdx.x * TILE;
  A += (long long)b * sA;
  B += (long long)b * sB;
  const int tid = threadIdx.x;
  const int tx = tid & 15;              // -> n micro col
  const int ty = tid >> 4;              // -> m micro row

  float acc[8][8];
#pragma unroll
  for (int i = 0; i < 8; ++i)
#pragma unroll
    for (int j = 0; j < 8; ++j) acc[i][j] = 0.0f;

  const int ar  = tid >> 1;             // 0..127 row
  const int akc = (tid & 1) * 8;        // 0 or 8

  for (int k0 = 0; k0 < Kd; k0 += BKC) {
    { // stage A (always row-major, K contiguous)
      const float* pa = &A[(long long)(m0 + ar) * lda + k0 + akc];
      float4 a0 = reinterpret_cast<const float4*>(pa)[0];
      float4 a1 = reinterpret_cast<const float4*>(pa)[1];
      As[akc + 0][ar] = a0.x; As[akc + 1][ar] = a0.y;
      As[akc + 2][ar] = a0.z; As[akc + 3][ar] = a0.w;
      As[akc + 4][ar] = a1.x; As[akc + 5][ar] = a1.y;
      As[akc + 6][ar] = a1.z; As[akc + 7][ar] = a1.w;
    }
    if (BT) { // B[N][K]
      const float* pb = &B[(long long)(n0 + ar) * ldb + k0 + akc];
      float4 b0 = reinterpret_cast<const float4*>(pb)[0];
      float4 b1 = reinterpret_cast<const float4*>(pb)[1];
      Bs[akc + 0][ar] = b0.x; Bs[akc + 1][ar] = b0.y;
      Bs[akc + 2][ar] = b0.z; Bs[akc + 3][ar] = b0.w;
      Bs[akc + 4][ar] = b1.x; Bs[akc + 5][ar] = b1.y;
      Bs[akc + 6][ar] = b1.z; Bs[akc + 7][ar] = b1.w;
    } else {  // B[K][N]
      const int br = tid >> 4;          // 0..15 k row
      const int bc = (tid & 15) * 8;    // 0..120 col
      const float* pb = &B[(long long)(k0 + br) * ldb + n0 + bc];
      float4 b0 = reinterpret_cast<const float4*>(pb)[0];
      float4 b1 = reinterpret_cast<const float4*>(pb)[1];
      *reinterpret_cast<float4*>(&Bs[br][bc])     = b0;
      *reinterpret_cast<float4*>(&Bs[br][bc + 4]) = b1;
    }
    __syncthreads();
#pragma unroll
    for (int kk = 0; kk < BKC; ++kk) {
      float a[8], bb[8];
      *(float4*)&a[0]  = *(const float4*)&As[kk][ty * 8];
      *(float4*)&a[4]  = *(const float4*)&As[kk][ty * 8 + 4];
      *(float4*)&bb[0] = *(const float4*)&Bs[kk][tx * 8];
      *(float4*)&bb[4] = *(const float4*)&Bs[kk][tx * 8 + 4];
#pragma unroll
      for (int i = 0; i < 8; ++i)
#pragma unroll
        for (int j = 0; j < 8; ++j)
          acc[i][j] = fmaf(a[i], bb[j], acc[i][j]);
    }
    __syncthreads();
  }

  if (EPI <= 1) {
    C += (long long)b * sC;
#pragma unroll
    for (int i = 0; i < 8; ++i) {
      float o[8];
#pragma unroll
      for (int j = 0; j < 8; ++j)
        o[j] = (EPI == 1) ? fast_tanh(acc[i][j]) : acc[i][j];
      float* pc = &C[(long long)(m0 + ty * 8 + i) * ldc + n0 + tx * 8];
      reinterpret_cast<float4*>(pc)[0] = *(float4*)&o[0];
      reinterpret_cast<float4*>(pc)[1] = *(float4*)&o[4];
    }
  } else {
    const float* bbase = bias + (long long)b * sBias;
    float whr[8];
#pragma unroll
    for (int i = 0; i < 8; ++i) whr[i] = wh[m0 + ty * 8 + i];
    float zp[8] = {0, 0, 0, 0, 0, 0, 0, 0};
#pragma unroll
    for (int i = 0; i < 8; ++i) {
      const float* pb2 = &bbase[(long long)(m0 + ty * 8 + i) * ldbias + n0 + tx * 8];
      float4 c0 = reinterpret_cast<const float4*>(pb2)[0];
      float4 c1 = reinterpret_cast<const float4*>(pb2)[1];
      float bv[8] = {c0.x, c0.y, c0.z, c0.w, c1.x, c1.y, c1.z, c1.w};
#pragma unroll
      for (int j = 0; j < 8; ++j)
        zp[j] += whr[i] * fast_tanh(acc[i][j] + bv[j]);
    }
    __syncthreads();
    float* red = &As[0][0];             // 16*128 fits in 16*(TILE+4)
#pragma unroll
    for (int j = 0; j < 8; ++j) red[ty * 128 + tx * 8 + j] = zp[j];
    __syncthreads();
    if (tid < 128) {
      float z = 0.0f;
#pragma unroll
      for (int g = 0; g < 16; ++g) z += red[g * 128 + tid];
      zout[(long long)b * sZ + n0 + tid] = z;
    }
  }
}

__global__ void pad_weights(const float* __restrict__ Ws, const float* __restrict__ Wc,
                            const float* __restrict__ whs, const float* __restrict__ whc,
                            float* __restrict__ Ws2, float* __restrict__ Wc2,
                            float* __restrict__ whs2, float* __restrict__ whc2)
{
  const int r = blockIdx.x;             // 0..127
  const int which = blockIdx.y;         // 0: Ws, 1: Wc
  const int c = threadIdx.x;            // 0..255
  const float* src = which ? Wc : Ws;
  float* dst = which ? Wc2 : Ws2;
  dst[r * 256 + c] = (r < 80) ? src[r * 256 + c] : 0.0f;
  if (r == 0 && c < 128) {
    const float* wsrc = which ? whc : whs;
    float* wdst = which ? whc2 : whs2;
    wdst[c] = (c < 80) ? wsrc[c] : 0.0f;
  }
}

__global__ __launch_bounds__(256) void finalize(
    const float* __restrict__ content, const float* __restrict__ comments,
    const float* __restrict__ zs, const float* __restrict__ zc,
    float* __restrict__ out)
{
  const int b = blockIdx.x;
  const int tid = threadIdx.x;
  __shared__ float w[512];
  __shared__ float red[256];
  for (int half = 0; half < 2; ++half) {
    const float* z = (half ? zc : zs) + b * 512;
    const float* X = (half ? comments : content) + (long long)b * 512 * 256;
    float v0 = z[tid], v1 = z[tid + 256];
    red[tid] = fmaxf(v0, v1);
    __syncthreads();
    for (int s = 128; s > 0; s >>= 1) {
      if (tid < s) red[tid] = fmaxf(red[tid], red[tid + s]);
      __syncthreads();
    }
    float mx = red[0];
    __syncthreads();
    float e0 = __expf(v0 - mx), e1 = __expf(v1 - mx);
    red[tid] = e0 + e1;
    __syncthreads();
    for (int s = 128; s > 0; s >>= 1) {
      if (tid < s) red[tid] += red[tid + s];
      __syncthreads();
    }
    float inv = 1.0f / red[0];
    __syncthreads();
    w[tid] = e0 * inv;
    w[tid + 256] = e1 * inv;
    __syncthreads();
    float acc = 0.0f;
    for (int r = 0; r < 512; ++r)
      acc = fmaf(w[r], X[(long long)r * 256 + tid], acc);
    out[(long long)b * 512 + half * 256 + tid] = acc;
    __syncthreads();
  }
}

extern "C" void kernel_launch(void* const* d_in, const int* in_sizes, int n_in,
                              void* d_out, int out_size, void* d_ws, size_t ws_size,
                              hipStream_t stream) {
  (void)in_sizes; (void)n_in; (void)out_size; (void)ws_size;
  const float* content  = (const float*)d_in[0];
  const float* comments = (const float*)d_in[1];
  const float* Wl  = (const float*)d_in[2];
  const float* Wc  = (const float*)d_in[3];
  const float* Ws  = (const float*)d_in[4];
  const float* whs = (const float*)d_in[5];
  const float* whc = (const float*)d_in[6];
  float* out = (float*)d_out;
  float* ws  = (float*)d_ws;

  const long long B = 128, N = 512, T = 512, D = 256;

  // workspace layout (floats)
  float* Ws2  = ws;                       // 128*256
  float* Wc2  = Ws2 + 128 * 256;          // 128*256
  float* whs2 = Wc2 + 128 * 256;          // 128
  float* whc2 = whs2 + 128;               // 128
  float* zs   = whc2 + 128;               // B*512
  float* zc   = zs + B * 512;             // B*512
  float* Lb   = zc + B * 512;             // B*T*N   (134 MB)
  float* CWb  = Lb + B * T * N;           // B*T*D   (67 MB)
  float* Sc2  = CWb;                      // B*128*512  (aliases CW; written after L)
  float* Cc2  = CWb + B * 128 * 512;      // B*128*512

  dim3 blk(256);

  // 1. pad weights (K 80 -> 128 with zeros)
  pad_weights<<<dim3(128, 2), blk, 0, stream>>>(Ws, Wc, whs, whc, Ws2, Wc2, whs2, whc2);

  // 2. CW = comments @ Wl   (NN, M=512, N=256, K=256)
  gemm128<0, 0><<<dim3(2, 4, B), blk, 0, stream>>>(
      comments, 256, T * D, Wl, 256, 0, CWb, 256, T * D,
      nullptr, 0, 0, nullptr, nullptr, 0, 256);

  // 3. L = tanh(CW @ content^T)  (NT, M=512, N=512, K=256)
  gemm128<1, 1><<<dim3(4, 4, B), blk, 0, stream>>>(
      CWb, 256, T * D, content, 256, N * D, Lb, 512, T * N,
      nullptr, 0, 0, nullptr, nullptr, 0, 256);

  // 4. Sc2 = Ws2 @ content^T  (NT, M=128, N=512, K=256)  [overwrites CW region]
  gemm128<1, 0><<<dim3(4, 1, B), blk, 0, stream>>>(
      Ws2, 256, 0, content, 256, N * D, Sc2, 512, 128 * 512,
      nullptr, 0, 0, nullptr, nullptr, 0, 256);

  // 5. Cc2 = Wc2 @ comments^T
  gemm128<1, 0><<<dim3(4, 1, B), blk, 0, stream>>>(
      Wc2, 256, 0, comments, 256, T * D, Cc2, 512, 128 * 512,
      nullptr, 0, 0, nullptr, nullptr, 0, 256);

  // 6. zs[n] = sum_k whs[k] * tanh(Sc2[k,n] + sum_t Cc2[k,t] L[t,n])   (NN, K=512)
  gemm128<0, 2><<<dim3(4, 1, B), blk, 0, stream>>>(
      Cc2, 512, 128 * 512, Lb, 512, T * N, nullptr, 0, 0,
      Sc2, 512, 128 * 512, whs2, zs, 512, 512);

  // 7. zc[t] = sum_k whc[k] * tanh(Cc2[k,t] + sum_n Sc2[k,n] L[t,n])   (NT, K=512)
  gemm128<1, 2><<<dim3(4, 1, B), blk, 0, stream>>>(
      Sc2, 512, 128 * 512, Lb, 512, T * N, nullptr, 0, 0,
      Cc2, 512, 128 * 512, whc2, zc, 512, 512);

  // 8. softmax + attention pooling
  finalize<<<dim3(128), blk, 0, stream>>>(content, comments, zs, zc, out);
}

// Round 4
// 512.060 us; speedup vs baseline: 1.3345x; 1.3345x over previous
//
#include <hip/hip_runtime.h>

typedef _Float16 f16;
typedef __attribute__((ext_vector_type(4))) _Float16 f16x4;
typedef __attribute__((ext_vector_type(8))) _Float16 f16x8;
typedef __attribute__((ext_vector_type(4))) float f32x4;

__device__ __forceinline__ void fsplit(float v, f16& h, f16& l) {
  h = (f16)v;
  l = (f16)(v - (float)h);
}
__device__ __forceinline__ float fast_tanh(float x) {
  float ax = fabsf(x);
  float e = __expf(2.0f * ax);
  float r = 1.0f - 2.0f / (e + 1.0f);
  return copysignf(r, x);
}

#define GLD16(g, l) __builtin_amdgcn_global_load_lds( \
    (const __attribute__((address_space(1))) unsigned int*)(g), \
    (__attribute__((address_space(3))) unsigned int*)(l), 16, 0, 0)

struct GemmArgs {
  const f16* Ah; const f16* Al; int lda; long long sA;
  const f16* Bh; const f16* Bl; int ldb; long long sB;
  f16* Ch; f16* Cl; int ldc; long long sC;
  f16* Th; f16* Tl; int ldt; long long sT;
  const float* wh; float* z;
};

// ---------------------------------------------------------------------------
// Split-fp16 MFMA GEMM: D = A*B^T, A[M][K] hi/lo, B[N][K] hi/lo (both NT).
// 128x128 tile, BK=32, 4 waves (2x2 of 64x64), 4x4 frags of 16x16x32 MFMA.
// 3-product split: AhBh + AhBl + AlBh  (rel err ~2^-23, near-f32).
// LDS [row][k], 16B slots XOR-swizzled by (row&3); swizzle applied on the
// GLOBAL source address (global_load_lds dest must stay linear).
// EPI 0: store hi/lo.  EPI 1: tanh -> store hi/lo + transposed hi/lo.
// EPI 2: z[n] = sum_m wh[m]*tanh(acc + bias[m][n]); bias via Ch/Cl.
// NSETS=2: blockIdx.y selects operand set (merged small GEMMs), m0=0.
// ---------------------------------------------------------------------------
template<int EPI, int NSETS>
__global__ __launch_bounds__(256, 2) void mgemm(GemmArgs g0, GemmArgs g1, int Kd)
{
  __shared__ f16 sAh[4096], sAl[4096], sBh[4096], sBl[4096];
  const GemmArgs& g = (NSETS == 2 && blockIdx.y == 1) ? g1 : g0;
  const int b = blockIdx.z;
  const int m0 = (NSETS == 2) ? 0 : blockIdx.y * 128;
  const int n0 = blockIdx.x * 128;
  const int tid = threadIdx.x;
  const int lane = tid & 63;
  const int wid = tid >> 6;
  const int wrow = (wid >> 1) * 64, wcol = (wid & 1) * 64;
  const int lda = g.lda, ldb = g.ldb;

  const f16* Agh = g.Ah + (long long)b * g.sA;
  const f16* Agl = g.Al + (long long)b * g.sA;
  const f16* Bgh = g.Bh + (long long)b * g.sB;
  const f16* Bgl = g.Bl + (long long)b * g.sB;

  f32x4 acc[4][4];
#pragma unroll
  for (int i = 0; i < 4; ++i)
#pragma unroll
    for (int j = 0; j < 4; ++j) acc[i][j] = f32x4{0.f, 0.f, 0.f, 0.f};

  // staging: thread -> (row = tid>>2 (+64), 16B slot = tid&3); source k-slot
  // pre-swizzled so LDS dest stays linear (tid*16B).
  const int srow = tid >> 2;
  const int sq = tid & 3;
  const int gs0 = ((sq ^ (srow & 3)) * 8);
  const long long gaA0 = (long long)(m0 + srow) * lda + gs0;
  const long long gaA1 = (long long)(m0 + srow + 64) * lda + gs0;
  const long long gaB0 = (long long)(n0 + srow) * ldb + gs0;
  const long long gaB1 = (long long)(n0 + srow + 64) * ldb + gs0;
  const int l0 = tid * 8, l1 = tid * 8 + 2048;

  // frag read offsets (swizzled slot = kg ^ (row&3))
  const int rl = lane & 15, kg = lane >> 4;
  int aoff[4], boff[4];
#pragma unroll
  for (int i = 0; i < 4; ++i) {
    int rowa = wrow + i * 16 + rl;
    aoff[i] = rowa * 32 + ((kg ^ (rowa & 3)) * 8);
    int rowb = wcol + i * 16 + rl;
    boff[i] = rowb * 32 + ((kg ^ (rowb & 3)) * 8);
  }

  for (int k0 = 0; k0 < Kd; k0 += 32) {
    GLD16(Agh + gaA0 + k0, sAh + l0);
    GLD16(Agh + gaA1 + k0, sAh + l1);
    GLD16(Agl + gaA0 + k0, sAl + l0);
    GLD16(Agl + gaA1 + k0, sAl + l1);
    GLD16(Bgh + gaB0 + k0, sBh + l0);
    GLD16(Bgh + gaB1 + k0, sBh + l1);
    GLD16(Bgl + gaB0 + k0, sBl + l0);
    GLD16(Bgl + gaB1 + k0, sBl + l1);
    __syncthreads();   // compiler drains vmcnt before s_barrier

    f16x8 fah[4], fal[4], fbh[4], fbl[4];
#pragma unroll
    for (int i = 0; i < 4; ++i) {
      fah[i] = *(const f16x8*)&sAh[aoff[i]];
      fal[i] = *(const f16x8*)&sAl[aoff[i]];
      fbh[i] = *(const f16x8*)&sBh[boff[i]];
      fbl[i] = *(const f16x8*)&sBl[boff[i]];
    }
#pragma unroll
    for (int i = 0; i < 4; ++i)
#pragma unroll
      for (int j = 0; j < 4; ++j) {
        acc[i][j] = __builtin_amdgcn_mfma_f32_16x16x32_f16(fah[i], fbh[j], acc[i][j], 0, 0, 0);
        acc[i][j] = __builtin_amdgcn_mfma_f32_16x16x32_f16(fah[i], fbl[j], acc[i][j], 0, 0, 0);
        acc[i][j] = __builtin_amdgcn_mfma_f32_16x16x32_f16(fal[i], fbh[j], acc[i][j], 0, 0, 0);
      }
    __syncthreads();
  }

  // C/D layout (measured, m89): col = lane&15, row = (lane>>4)*4 + reg
  if (EPI == 0) {
    f16* ch = g.Ch + (long long)b * g.sC;
    f16* cl = g.Cl + (long long)b * g.sC;
    const int ldc = g.ldc;
#pragma unroll
    for (int i = 0; i < 4; ++i)
#pragma unroll
      for (int j = 0; j < 4; ++j) {
        int gcol = n0 + wcol + j * 16 + rl;
#pragma unroll
        for (int q = 0; q < 4; ++q) {
          int grow = m0 + wrow + i * 16 + kg * 4 + q;
          f16 h, l;
          fsplit(acc[i][j][q], h, l);
          ch[(long long)grow * ldc + gcol] = h;
          cl[(long long)grow * ldc + gcol] = l;
        }
      }
  } else if (EPI == 1) {
    f16* ch = g.Ch + (long long)b * g.sC;
    f16* cl = g.Cl + (long long)b * g.sC;
    f16* th = g.Th + (long long)b * g.sT;
    f16* tl = g.Tl + (long long)b * g.sT;
    const int ldc = g.ldc, ldt = g.ldt;
#pragma unroll
    for (int i = 0; i < 4; ++i)
#pragma unroll
      for (int j = 0; j < 4; ++j) {
        int gcol = n0 + wcol + j * 16 + rl;
        int rb = m0 + wrow + i * 16 + kg * 4;
        f16x4 ph, pl;
#pragma unroll
        for (int q = 0; q < 4; ++q) {
          float v = fast_tanh(acc[i][j][q]);
          f16 h, l;
          fsplit(v, h, l);
          ch[(long long)(rb + q) * ldc + gcol] = h;
          cl[(long long)(rb + q) * ldc + gcol] = l;
          ph[q] = h; pl[q] = l;
        }
        *(f16x4*)&th[(long long)gcol * ldt + rb] = ph;
        *(f16x4*)&tl[(long long)gcol * ldt + rb] = pl;
      }
  } else {
    const f16* bh = g.Ch + (long long)b * g.sC;
    const f16* bl = g.Cl + (long long)b * g.sC;
    const int ldc = g.ldc;
    float zp[4] = {0.f, 0.f, 0.f, 0.f};
#pragma unroll
    for (int i = 0; i < 4; ++i)
#pragma unroll
      for (int q = 0; q < 4; ++q) {
        int grow = m0 + wrow + i * 16 + kg * 4 + q;
        float wv = g.wh[grow];
#pragma unroll
        for (int j = 0; j < 4; ++j) {
          int gcol = n0 + wcol + j * 16 + rl;
          long long bi = (long long)grow * ldc + gcol;
          float bias = (float)bh[bi] + (float)bl[bi];
          zp[j] += wv * fast_tanh(acc[i][j][q] + bias);
        }
      }
#pragma unroll
    for (int j = 0; j < 4; ++j) {  // reduce the 4 kg-lanes sharing a column
      zp[j] += __shfl_xor(zp[j], 16);
      zp[j] += __shfl_xor(zp[j], 32);
    }
    __syncthreads();
    float* zred = (float*)sAh;  // 256 floats, reuse staging LDS
    if (lane < 16) {
#pragma unroll
      for (int j = 0; j < 4; ++j)
        zred[(wid >> 1) * 128 + wcol + j * 16 + lane] = zp[j];
    }
    __syncthreads();
    if (tid < 128)
      g.z[(long long)b * 512 + n0 + tid] = zred[tid] + zred[128 + tid];
  }
}

// ---------------------------------------------------------------------------
__global__ void cvt_hilo2(const float* __restrict__ s0, f16* __restrict__ h0,
                          f16* __restrict__ l0_,
                          const float* __restrict__ s1, f16* __restrict__ h1,
                          f16* __restrict__ l1_, int n4)
{
  const float* src = blockIdx.y ? s1 : s0;
  f16* hi = blockIdx.y ? h1 : h0;
  f16* lo = blockIdx.y ? l1_ : l0_;
  int stride = gridDim.x * blockDim.x;
  for (int i = blockIdx.x * blockDim.x + threadIdx.x; i < n4; i += stride) {
    f32x4 v = ((const f32x4*)src)[i];
    f16x4 h, l;
#pragma unroll
    for (int c = 0; c < 4; ++c) {
      f16 hh, ll;
      fsplit(v[c], hh, ll);
      h[c] = hh; l[c] = ll;
    }
    ((f16x4*)hi)[i] = h;
    ((f16x4*)lo)[i] = l;
  }
}

__global__ void prep_weights(const float* __restrict__ Wl, const float* __restrict__ Ws,
                             const float* __restrict__ Wc, const float* __restrict__ whs,
                             const float* __restrict__ whc,
                             f16* __restrict__ WlT_hi, f16* __restrict__ WlT_lo,
                             f16* __restrict__ Ws2_hi, f16* __restrict__ Ws2_lo,
                             f16* __restrict__ Wc2_hi, f16* __restrict__ Wc2_lo,
                             float* __restrict__ whs2, float* __restrict__ whc2)
{
  const int blk = blockIdx.x, t = threadIdx.x;
  if (blk < 256) {            // WlT[D][d] = Wl[d][D]
    f16 h, l;
    fsplit(Wl[t * 256 + blk], h, l);
    WlT_hi[blk * 256 + t] = h;
    WlT_lo[blk * 256 + t] = l;
  } else if (blk < 384) {     // Ws padded K 80->128
    int k = blk - 256;
    f16 h, l;
    fsplit((k < 80) ? Ws[k * 256 + t] : 0.f, h, l);
    Ws2_hi[k * 256 + t] = h;
    Ws2_lo[k * 256 + t] = l;
  } else if (blk < 512) {     // Wc padded
    int k = blk - 384;
    f16 h, l;
    fsplit((k < 80) ? Wc[k * 256 + t] : 0.f, h, l);
    Wc2_hi[k * 256 + t] = h;
    Wc2_lo[k * 256 + t] = l;
  } else {
    if (t < 128) whs2[t] = (t < 80) ? whs[t] : 0.f;
    else { int k = t - 128; whc2[k] = (k < 80) ? whc[k] : 0.f; }
  }
}

__global__ __launch_bounds__(256) void finalize(
    const float* __restrict__ content, const float* __restrict__ comments,
    const float* __restrict__ zs, const float* __restrict__ zc,
    float* __restrict__ out)
{
  const int b = blockIdx.x;
  const int half = blockIdx.y;
  const int tid = threadIdx.x;
  __shared__ float w[512];
  __shared__ float red[256];
  const float* z = (half ? zc : zs) + b * 512;
  const float* X = (half ? comments : content) + (long long)b * 512 * 256;
  float v0 = z[tid], v1 = z[tid + 256];
  red[tid] = fmaxf(v0, v1);
  __syncthreads();
  for (int s = 128; s > 0; s >>= 1) {
    if (tid < s) red[tid] = fmaxf(red[tid], red[tid + s]);
    __syncthreads();
  }
  float mx = red[0];
  __syncthreads();
  float e0 = __expf(v0 - mx), e1 = __expf(v1 - mx);
  red[tid] = e0 + e1;
  __syncthreads();
  for (int s = 128; s > 0; s >>= 1) {
    if (tid < s) red[tid] += red[tid + s];
    __syncthreads();
  }
  float inv = 1.0f / red[0];
  w[tid] = e0 * inv;
  w[tid + 256] = e1 * inv;
  __syncthreads();
  float acc2 = 0.f;
  for (int r = 0; r < 512; ++r)
    acc2 = fmaf(w[r], X[(long long)r * 256 + tid], acc2);
  out[(long long)b * 512 + half * 256 + tid] = acc2;
}

// ---------------------------------------------------------------------------
extern "C" void kernel_launch(void* const* d_in, const int* in_sizes, int n_in,
                              void* d_out, int out_size, void* d_ws, size_t ws_size,
                              hipStream_t stream) {
  (void)in_sizes; (void)n_in; (void)out_size;
  const float* content  = (const float*)d_in[0];
  const float* comments = (const float*)d_in[1];
  const float* Wl  = (const float*)d_in[2];
  const float* Wc  = (const float*)d_in[3];
  const float* Ws  = (const float*)d_in[4];
  const float* whs = (const float*)d_in[5];
  const float* whc = (const float*)d_in[6];
  float* out = (float*)d_out;

  // Batch-chunked: peak ws = G*4 MiB + ~2 MiB; G adapts to the real ws_size.
  int G = 32;
  if (ws_size >= 4194304ULL * 128 + (16ULL << 20))      G = 128;
  else if (ws_size >= 4194304ULL * 64 + (16ULL << 20))  G = 64;

  char* base = (char*)d_ws;
  size_t off = 0;
  auto alloc = [&](size_t bytes) -> char* {
    char* p = base + off;
    off = (off + bytes + 255) & ~(size_t)255;
    return p;
  };

  const long long PBcm = 512 * 256;   // per-batch elems, content/comments
  const long long PBL  = 512 * 512;   // per-batch elems, L / LT
  const long long PBsc = 128 * 512;   // per-batch elems, Sc / Cc

  f16* c_hi = (f16*)alloc((size_t)G * PBcm * 2);
  f16* c_lo = (f16*)alloc((size_t)G * PBcm * 2);
  f16* m_hi = (f16*)alloc((size_t)G * PBcm * 2);
  f16* m_lo = (f16*)alloc((size_t)G * PBcm * 2);
  f16* CW_hi = (f16*)alloc((size_t)G * PBcm * 2);
  f16* CW_lo = (f16*)alloc((size_t)G * PBcm * 2);
  f16* Sc_hi = (f16*)alloc((size_t)G * PBsc * 2);
  f16* Sc_lo = (f16*)alloc((size_t)G * PBsc * 2);
  f16* Cc_hi = (f16*)alloc((size_t)G * PBsc * 2);
  f16* Cc_lo = (f16*)alloc((size_t)G * PBsc * 2);
  f16* L_hi  = (f16*)alloc((size_t)G * PBL * 2);
  f16* L_lo  = (f16*)alloc((size_t)G * PBL * 2);
  f16* LT_hi = (f16*)alloc((size_t)G * PBL * 2);
  f16* LT_lo = (f16*)alloc((size_t)G * PBL * 2);
  f16* WlT_hi = (f16*)alloc(256 * 256 * 2);
  f16* WlT_lo = (f16*)alloc(256 * 256 * 2);
  f16* Ws2_hi = (f16*)alloc(128 * 256 * 2);
  f16* Ws2_lo = (f16*)alloc(128 * 256 * 2);
  f16* Wc2_hi = (f16*)alloc(128 * 256 * 2);
  f16* Wc2_lo = (f16*)alloc(128 * 256 * 2);
  float* whs2 = (float*)alloc(512);
  float* whc2 = (float*)alloc(512);
  float* zs = (float*)alloc(128 * 512 * 4);
  float* zc = (float*)alloc(128 * 512 * 4);

  dim3 blk(256);

  prep_weights<<<dim3(513), blk, 0, stream>>>(Wl, Ws, Wc, whs, whc,
      WlT_hi, WlT_lo, Ws2_hi, Ws2_lo, Wc2_hi, Wc2_lo, whs2, whc2);

  for (int c0 = 0; c0 < 128; c0 += G) {
    // 1. convert this chunk's inputs to hi/lo f16
    cvt_hilo2<<<dim3(1024, 2), blk, 0, stream>>>(
        content + (long long)c0 * PBcm, c_hi, c_lo,
        comments + (long long)c0 * PBcm, m_hi, m_lo,
        (int)((long long)G * PBcm / 4));

    GemmArgs a, b2;

    // 2. CW = comments @ Wl   (A=comments[t][d], B=WlT[D][d], M=512,N=256,K=256)
    a = {m_hi, m_lo, 256, PBcm,  WlT_hi, WlT_lo, 256, 0,
         CW_hi, CW_lo, 256, PBcm,  nullptr, nullptr, 0, 0,  nullptr, nullptr};
    mgemm<0, 1><<<dim3(2, 4, G), blk, 0, stream>>>(a, a, 256);

    // 3. L = tanh(CW @ content^T) -> L[t][n] + LT[n][t], hi/lo
    a = {CW_hi, CW_lo, 256, PBcm,  c_hi, c_lo, 256, PBcm,
         L_hi, L_lo, 512, PBL,  LT_hi, LT_lo, 512, PBL,  nullptr, nullptr};
    mgemm<1, 1><<<dim3(4, 4, G), blk, 0, stream>>>(a, a, 256);

    // 4+5. Sc = Ws2 @ content^T ; Cc = Wc2 @ comments^T  (merged via y)
    a  = {Ws2_hi, Ws2_lo, 256, 0,  c_hi, c_lo, 256, PBcm,
          Sc_hi, Sc_lo, 512, PBsc,  nullptr, nullptr, 0, 0,  nullptr, nullptr};
    b2 = {Wc2_hi, Wc2_lo, 256, 0,  m_hi, m_lo, 256, PBcm,
          Cc_hi, Cc_lo, 512, PBsc,  nullptr, nullptr, 0, 0,  nullptr, nullptr};
    mgemm<0, 2><<<dim3(4, 2, G), blk, 0, stream>>>(a, b2, 256);

    // 6+7. zs[n] = sum_k whs[k] tanh(Sc[k,n] + Cc@LT) ;
    //      zc[t] = sum_k whc[k] tanh(Cc[k,t] + Sc@L)   (merged via y, K=512)
    a  = {Cc_hi, Cc_lo, 512, PBsc,  LT_hi, LT_lo, 512, PBL,
          Sc_hi, Sc_lo, 512, PBsc,  nullptr, nullptr, 0, 0,
          whs2, zs + (long long)c0 * 512};
    b2 = {Sc_hi, Sc_lo, 512, PBsc,  L_hi, L_lo, 512, PBL,
          Cc_hi, Cc_lo, 512, PBsc,  nullptr, nullptr, 0, 0,
          whc2, zc + (long long)c0 * 512};
    mgemm<2, 2><<<dim3(4, 2, G), blk, 0, stream>>>(a, b2, 512);
  }

  // 8. softmax + attention pooling
  finalize<<<dim3(128, 2), blk, 0, stream>>>(content, comments, zs, zc, out);
}

// Round 5
// 453.994 us; speedup vs baseline: 1.5052x; 1.1279x over previous
//
#include <hip/hip_runtime.h>

typedef _Float16 f16;
typedef __attribute__((ext_vector_type(4))) _Float16 f16x4;
typedef __attribute__((ext_vector_type(8))) _Float16 f16x8;
typedef __attribute__((ext_vector_type(4))) float f32x4;

__device__ __forceinline__ void fsplit(float v, f16& h, f16& l) {
  h = (f16)v;
  l = (f16)(v - (float)h);
}
__device__ __forceinline__ float fast_tanh(float x) {
  float ax = fabsf(x);
  float e = __expf(2.0f * ax);
  float r = 1.0f - 2.0f / (e + 1.0f);
  return copysignf(r, x);
}

#define GLD16(g, l) __builtin_amdgcn_global_load_lds( \
    (const __attribute__((address_space(1))) unsigned int*)(g), \
    (__attribute__((address_space(3))) unsigned int*)(l), 16, 0, 0)

struct GemmArgs {
  const f16* Ah; const f16* Al; int lda; long long sA;
  const f16* Bh; const f16* Bl; int ldb; long long sB;
  f16* Ch; f16* Cl; int ldc; long long sC;
  f16* Th; f16* Tl; int ldt; long long sT;
  const float* wh; float* z;
};

// ---------------------------------------------------------------------------
// Split-fp16 MFMA GEMM: D = A*B^T, A[M][K] hi/lo, B[N][K] hi/lo (both NT).
// 128x128 tile, BK=32, 4 waves (2x2 of 64x64), 4x4 frags of 16x16x32 MFMA.
// 3-product split: AhBh + AhBl + AlBh  (rel err ~2^-23, near-f32).
// K-loop: 2-phase LDS double-buffer (2x32KB), prefetch next tile's
// global_load_lds before compute, ONE __syncthreads per step (its vmcnt(0)
// drain doubles as prefetch-completion wait).
// Epilogues: acc -> f16 hi/lo regs once, then per output plane stage through
// a padded LDS image [128][136] and store f16x8/lane, 256B-contig per row.
// EPI 0: store hi/lo.  EPI 1: tanh -> store hi/lo + transposed hi/lo.
// EPI 2: z[n] = sum_m wh[m]*tanh(acc + bias[m][n]); bias via Ch/Cl.
// NSETS=2: blockIdx.y selects operand set (merged small GEMMs), m0=0.
// ---------------------------------------------------------------------------
template<int EPI, int NSETS>
__global__ __launch_bounds__(256, 2) void mgemm(GemmArgs g0, GemmArgs g1, int Kd)
{
  __shared__ char smem[65536];   // 2 x (4 planes x 8KB) staging; epilogue image
  const GemmArgs& g = (NSETS == 2 && blockIdx.y == 1) ? g1 : g0;
  const int b = blockIdx.z;
  const int m0 = (NSETS == 2) ? 0 : blockIdx.y * 128;
  const int n0 = blockIdx.x * 128;
  const int tid = threadIdx.x;
  const int lane = tid & 63;
  const int wid = tid >> 6;
  const int wrow = (wid >> 1) * 64, wcol = (wid & 1) * 64;
  const int lda = g.lda, ldb = g.ldb;

  const f16* Agh = g.Ah + (long long)b * g.sA;
  const f16* Agl = g.Al + (long long)b * g.sA;
  const f16* Bgh = g.Bh + (long long)b * g.sB;
  const f16* Bgl = g.Bl + (long long)b * g.sB;

  f32x4 acc[4][4];
#pragma unroll
  for (int i = 0; i < 4; ++i)
#pragma unroll
    for (int j = 0; j < 4; ++j) acc[i][j] = f32x4{0.f, 0.f, 0.f, 0.f};

  // staging: thread -> (row = tid>>2 (+64), 16B slot = tid&3); source k-slot
  // pre-swizzled so LDS dest stays linear (tid*16B).
  const int srow = tid >> 2;
  const int sq = tid & 3;
  const int gs0 = ((sq ^ (srow & 3)) * 8);
  const long long gaA0 = (long long)(m0 + srow) * lda + gs0;
  const long long gaA1 = (long long)(m0 + srow + 64) * lda + gs0;
  const long long gaB0 = (long long)(n0 + srow) * ldb + gs0;
  const long long gaB1 = (long long)(n0 + srow + 64) * ldb + gs0;

  auto stage = [&](int k0, int bo) {
    char* pAh = smem + bo;
    char* pAl = smem + bo + 8192;
    char* pBh = smem + bo + 16384;
    char* pBl = smem + bo + 24576;
    GLD16(Agh + gaA0 + k0, pAh + tid * 16);
    GLD16(Agh + gaA1 + k0, pAh + 4096 + tid * 16);
    GLD16(Agl + gaA0 + k0, pAl + tid * 16);
    GLD16(Agl + gaA1 + k0, pAl + 4096 + tid * 16);
    GLD16(Bgh + gaB0 + k0, pBh + tid * 16);
    GLD16(Bgh + gaB1 + k0, pBh + 4096 + tid * 16);
    GLD16(Bgl + gaB0 + k0, pBl + tid * 16);
    GLD16(Bgl + gaB1 + k0, pBl + 4096 + tid * 16);
  };

  // frag read offsets (swizzled slot = kg ^ (row&3)), f16 elements
  const int rl = lane & 15, kg = lane >> 4;
  int aoff[4], boff[4];
#pragma unroll
  for (int i = 0; i < 4; ++i) {
    int rowa = wrow + i * 16 + rl;
    aoff[i] = rowa * 32 + ((kg ^ (rowa & 3)) * 8);
    int rowb = wcol + i * 16 + rl;
    boff[i] = rowb * 32 + ((kg ^ (rowb & 3)) * 8);
  }

  const int nt = Kd >> 5;
  int bufo = 0;
  stage(0, 0);
  __syncthreads();
  for (int t = 0; t < nt; ++t) {
    const int nb = bufo ^ 32768;
    if (t + 1 < nt) stage((t + 1) * 32, nb);   // prefetch overlaps compute

    const f16* sAh = (const f16*)(smem + bufo);
    const f16* sAl = (const f16*)(smem + bufo + 8192);
    const f16* sBh = (const f16*)(smem + bufo + 16384);
    const f16* sBl = (const f16*)(smem + bufo + 24576);
    f16x8 fah[4], fal[4], fbh[4], fbl[4];
#pragma unroll
    for (int i = 0; i < 4; ++i) {
      fah[i] = *(const f16x8*)&sAh[aoff[i]];
      fal[i] = *(const f16x8*)&sAl[aoff[i]];
      fbh[i] = *(const f16x8*)&sBh[boff[i]];
      fbl[i] = *(const f16x8*)&sBl[boff[i]];
    }
#pragma unroll
    for (int i = 0; i < 4; ++i)
#pragma unroll
      for (int j = 0; j < 4; ++j) {
        acc[i][j] = __builtin_amdgcn_mfma_f32_16x16x32_f16(fah[i], fbh[j], acc[i][j], 0, 0, 0);
        acc[i][j] = __builtin_amdgcn_mfma_f32_16x16x32_f16(fah[i], fbl[j], acc[i][j], 0, 0, 0);
        acc[i][j] = __builtin_amdgcn_mfma_f32_16x16x32_f16(fal[i], fbh[j], acc[i][j], 0, 0, 0);
      }
    __syncthreads();   // vmcnt(0) drain = prefetch landed; buffers swap safely
    bufo = nb;
  }

  // C/D layout (measured, m89): col = lane&15, row = (lane>>4)*4 + reg
  if (EPI <= 1) {
    // pack hi/lo f16 planes into registers once
    f16x4 ph[4][4], pl[4][4];
#pragma unroll
    for (int i = 0; i < 4; ++i)
#pragma unroll
      for (int j = 0; j < 4; ++j)
#pragma unroll
        for (int q = 0; q < 4; ++q) {
          float v = (EPI == 1) ? fast_tanh(acc[i][j][q]) : acc[i][j][q];
          f16 h, l; fsplit(v, h, l);
          ph[i][j][q] = h; pl[i][j][q] = l;
        }
    f16* img = (f16*)smem;            // [128][136] padded image
    const int q4 = lane >> 4, c16 = lane & 15;
    const int nplanes = (EPI == 1) ? 4 : 2;
#pragma unroll
    for (int plane = 0; plane < 4; ++plane) {
      if (plane >= nplanes) break;
      const int lo = plane & 1, tr = plane >> 1;
      __syncthreads();                // image free (previous reads done)
      if (!tr) {                      // [row=t][col=n]
#pragma unroll
        for (int i = 0; i < 4; ++i)
#pragma unroll
          for (int j = 0; j < 4; ++j)
#pragma unroll
            for (int q = 0; q < 4; ++q)
              img[(wrow + i * 16 + kg * 4 + q) * 136 + wcol + j * 16 + rl] =
                  lo ? pl[i][j][q] : ph[i][j][q];
      } else {                        // transposed image [row=n][col=t]
#pragma unroll
        for (int i = 0; i < 4; ++i)
#pragma unroll
          for (int j = 0; j < 4; ++j)
            *(f16x4*)&img[(wcol + j * 16 + rl) * 136 + wrow + i * 16 + kg * 4] =
                lo ? pl[i][j] : ph[i][j];
      }
      __syncthreads();
      f16* gb; int grow0, gcol0, ldg;
      if (!tr) { gb = (lo ? g.Cl : g.Ch) + (long long)b * g.sC; grow0 = m0; gcol0 = n0; ldg = g.ldc; }
      else     { gb = (lo ? g.Tl : g.Th) + (long long)b * g.sT; grow0 = n0; gcol0 = m0; ldg = g.ldt; }
#pragma unroll
      for (int it = 0; it < 8; ++it) {
        int r = it * 16 + wid * 4 + q4;
        *(f16x8*)&gb[(long long)(grow0 + r) * ldg + gcol0 + c16 * 8] =
            *(const f16x8*)&img[r * 136 + c16 * 8];
      }
    }
  } else {
    const f16* bh = g.Ch + (long long)b * g.sC;
    const f16* bl = g.Cl + (long long)b * g.sC;
    const int ldc = g.ldc;
    float zp[4] = {0.f, 0.f, 0.f, 0.f};
#pragma unroll
    for (int i = 0; i < 4; ++i)
#pragma unroll
      for (int q = 0; q < 4; ++q) {
        int grow = m0 + wrow + i * 16 + kg * 4 + q;
        float wv = g.wh[grow];
#pragma unroll
        for (int j = 0; j < 4; ++j) {
          int gcol = n0 + wcol + j * 16 + rl;
          long long bi = (long long)grow * ldc + gcol;
          float bias = (float)bh[bi] + (float)bl[bi];
          zp[j] += wv * fast_tanh(acc[i][j][q] + bias);
        }
      }
#pragma unroll
    for (int j = 0; j < 4; ++j) {  // reduce the 4 kg-lanes sharing a column
      zp[j] += __shfl_xor(zp[j], 16);
      zp[j] += __shfl_xor(zp[j], 32);
    }
    __syncthreads();
    float* zred = (float*)smem;
    if (lane < 16) {
#pragma unroll
      for (int j = 0; j < 4; ++j)
        zred[(wid >> 1) * 128 + wcol + j * 16 + lane] = zp[j];
    }
    __syncthreads();
    if (tid < 128)
      g.z[(long long)b * 512 + n0 + tid] = zred[tid] + zred[128 + tid];
  }
}

// ---------------------------------------------------------------------------
// hi planes go to ABSOLUTE batch offsets (persist for finalize); lo chunked.
__global__ void cvt_hilo2(const float* __restrict__ s0, f16* __restrict__ h0,
                          f16* __restrict__ l0_,
                          const float* __restrict__ s1, f16* __restrict__ h1,
                          f16* __restrict__ l1_, int n4)
{
  const float* src = blockIdx.y ? s1 : s0;
  f16* hi = blockIdx.y ? h1 : h0;
  f16* lo = blockIdx.y ? l1_ : l0_;
  int stride = gridDim.x * blockDim.x;
  for (int i = blockIdx.x * blockDim.x + threadIdx.x; i < n4; i += stride) {
    f32x4 v = ((const f32x4*)src)[i];
    f16x4 h, l;
#pragma unroll
    for (int c = 0; c < 4; ++c) {
      f16 hh, ll;
      fsplit(v[c], hh, ll);
      h[c] = hh; l[c] = ll;
    }
    ((f16x4*)hi)[i] = h;
    ((f16x4*)lo)[i] = l;
  }
}

__global__ void prep_weights(const float* __restrict__ Wl, const float* __restrict__ Ws,
                             const float* __restrict__ Wc, const float* __restrict__ whs,
                             const float* __restrict__ whc,
                             f16* __restrict__ WlT_hi, f16* __restrict__ WlT_lo,
                             f16* __restrict__ Ws2_hi, f16* __restrict__ Ws2_lo,
                             f16* __restrict__ Wc2_hi, f16* __restrict__ Wc2_lo,
                             float* __restrict__ whs2, float* __restrict__ whc2)
{
  const int blk = blockIdx.x, t = threadIdx.x;
  if (blk < 256) {            // WlT[D][d] = Wl[d][D]
    f16 h, l;
    fsplit(Wl[t * 256 + blk], h, l);
    WlT_hi[blk * 256 + t] = h;
    WlT_lo[blk * 256 + t] = l;
  } else if (blk < 384) {     // Ws padded K 80->128
    int k = blk - 256;
    f16 h, l;
    fsplit((k < 80) ? Ws[k * 256 + t] : 0.f, h, l);
    Ws2_hi[k * 256 + t] = h;
    Ws2_lo[k * 256 + t] = l;
  } else if (blk < 512) {     // Wc padded
    int k = blk - 384;
    f16 h, l;
    fsplit((k < 80) ? Wc[k * 256 + t] : 0.f, h, l);
    Wc2_hi[k * 256 + t] = h;
    Wc2_lo[k * 256 + t] = l;
  } else {
    if (t < 128) whs2[t] = (t < 80) ? whs[t] : 0.f;
    else { int k = t - 128; whc2[k] = (k < 80) ? whc[k] : 0.f; }
  }
}

__global__ __launch_bounds__(256) void finalize(
    const f16* __restrict__ content_h, const f16* __restrict__ comments_h,
    const float* __restrict__ zs, const float* __restrict__ zc,
    float* __restrict__ out)
{
  const int b = blockIdx.x;
  const int half = blockIdx.y;
  const int tid = threadIdx.x;
  __shared__ float w[512];
  __shared__ float red[256];
  const float* z = (half ? zc : zs) + b * 512;
  const f16* X = (half ? comments_h : content_h) + (long long)b * 512 * 256;
  float v0 = z[tid], v1 = z[tid + 256];
  red[tid] = fmaxf(v0, v1);
  __syncthreads();
  for (int s = 128; s > 0; s >>= 1) {
    if (tid < s) red[tid] = fmaxf(red[tid], red[tid + s]);
    __syncthreads();
  }
  float mx = red[0];
  __syncthreads();
  float e0 = __expf(v0 - mx), e1 = __expf(v1 - mx);
  red[tid] = e0 + e1;
  __syncthreads();
  for (int s = 128; s > 0; s >>= 1) {
    if (tid < s) red[tid] += red[tid + s];
    __syncthreads();
  }
  float inv = 1.0f / red[0];
  w[tid] = e0 * inv;
  w[tid + 256] = e1 * inv;
  __syncthreads();
  float acc2 = 0.f;
  for (int r = 0; r < 512; ++r)
    acc2 = fmaf(w[r], (float)X[(long long)r * 256 + tid], acc2);
  out[(long long)b * 512 + half * 256 + tid] = acc2;
}

// ---------------------------------------------------------------------------
extern "C" void kernel_launch(void* const* d_in, const int* in_sizes, int n_in,
                              void* d_out, int out_size, void* d_ws, size_t ws_size,
                              hipStream_t stream) {
  (void)in_sizes; (void)n_in; (void)out_size;
  const float* content  = (const float*)d_in[0];
  const float* comments = (const float*)d_in[1];
  const float* Wl  = (const float*)d_in[2];
  const float* Wc  = (const float*)d_in[3];
  const float* Ws  = (const float*)d_in[4];
  const float* whs = (const float*)d_in[5];
  const float* whc = (const float*)d_in[6];
  float* out = (float*)d_out;

  // ws: fixed 68 MB (full-batch hi planes + weights + z) + G*3.67 MB chunked.
  int G = 32;
  if      (ws_size >= 560ULL << 20) G = 128;
  else if (ws_size >= 320ULL << 20) G = 64;

  char* base = (char*)d_ws;
  size_t off = 0;
  auto alloc = [&](size_t bytes) -> char* {
    char* p = base + off;
    off = (off + bytes + 255) & ~(size_t)255;
    return p;
  };

  const long long PBcm = 512 * 256;   // per-batch elems, content/comments
  const long long PBL  = 512 * 512;   // per-batch elems, L / LT
  const long long PBsc = 128 * 512;   // per-batch elems, Sc / Cc

  // full-batch hi planes (finalize reads these)
  f16* c_hi = (f16*)alloc(128 * PBcm * 2);
  f16* m_hi = (f16*)alloc(128 * PBcm * 2);
  // chunked planes
  f16* c_lo = (f16*)alloc((size_t)G * PBcm * 2);
  f16* m_lo = (f16*)alloc((size_t)G * PBcm * 2);
  f16* CW_hi = (f16*)alloc((size_t)G * PBcm * 2);
  f16* CW_lo = (f16*)alloc((size_t)G * PBcm * 2);
  f16* Sc_hi = (f16*)alloc((size_t)G * PBsc * 2);
  f16* Sc_lo = (f16*)alloc((size_t)G * PBsc * 2);
  f16* Cc_hi = (f16*)alloc((size_t)G * PBsc * 2);
  f16* Cc_lo = (f16*)alloc((size_t)G * PBsc * 2);
  f16* L_hi  = (f16*)alloc((size_t)G * PBL * 2);
  f16* L_lo  = (f16*)alloc((size_t)G * PBL * 2);
  f16* LT_hi = (f16*)alloc((size_t)G * PBL * 2);
  f16* LT_lo = (f16*)alloc((size_t)G * PBL * 2);
  f16* WlT_hi = (f16*)alloc(256 * 256 * 2);
  f16* WlT_lo = (f16*)alloc(256 * 256 * 2);
  f16* Ws2_hi = (f16*)alloc(128 * 256 * 2);
  f16* Ws2_lo = (f16*)alloc(128 * 256 * 2);
  f16* Wc2_hi = (f16*)alloc(128 * 256 * 2);
  f16* Wc2_lo = (f16*)alloc(128 * 256 * 2);
  float* whs2 = (float*)alloc(512);
  float* whc2 = (float*)alloc(512);
  float* zs = (float*)alloc(128 * 512 * 4);
  float* zc = (float*)alloc(128 * 512 * 4);

  dim3 blk(256);

  prep_weights<<<dim3(513), blk, 0, stream>>>(Wl, Ws, Wc, whs, whc,
      WlT_hi, WlT_lo, Ws2_hi, Ws2_lo, Wc2_hi, Wc2_lo, whs2, whc2);

  for (int c0 = 0; c0 < 128; c0 += G) {
    // 1. convert chunk inputs: hi -> absolute offsets, lo -> chunk buffers
    cvt_hilo2<<<dim3(1024, 2), blk, 0, stream>>>(
        content + (long long)c0 * PBcm, c_hi + (long long)c0 * PBcm, c_lo,
        comments + (long long)c0 * PBcm, m_hi + (long long)c0 * PBcm, m_lo,
        (int)((long long)G * PBcm / 4));

    const f16* cchi = c_hi + (long long)c0 * PBcm;
    const f16* cmhi = m_hi + (long long)c0 * PBcm;
    GemmArgs a, b2;

    // 2. CW = comments @ Wl   (A=comments[t][d], B=WlT[D][d], M=512,N=256,K=256)
    a = {cmhi, m_lo, 256, PBcm,  WlT_hi, WlT_lo, 256, 0,
         CW_hi, CW_lo, 256, PBcm,  nullptr, nullptr, 0, 0,  nullptr, nullptr};
    mgemm<0, 1><<<dim3(2, 4, G), blk, 0, stream>>>(a, a, 256);

    // 3. L = tanh(CW @ content^T) -> L[t][n] + LT[n][t], hi/lo
    a = {CW_hi, CW_lo, 256, PBcm,  cchi, c_lo, 256, PBcm,
         L_hi, L_lo, 512, PBL,  LT_hi, LT_lo, 512, PBL,  nullptr, nullptr};
    mgemm<1, 1><<<dim3(4, 4, G), blk, 0, stream>>>(a, a, 256);

    // 4+5. Sc = Ws2 @ content^T ; Cc = Wc2 @ comments^T  (merged via y)
    a  = {Ws2_hi, Ws2_lo, 256, 0,  cchi, c_lo, 256, PBcm,
          Sc_hi, Sc_lo, 512, PBsc,  nullptr, nullptr, 0, 0,  nullptr, nullptr};
    b2 = {Wc2_hi, Wc2_lo, 256, 0,  cmhi, m_lo, 256, PBcm,
          Cc_hi, Cc_lo, 512, PBsc,  nullptr, nullptr, 0, 0,  nullptr, nullptr};
    mgemm<0, 2><<<dim3(4, 2, G), blk, 0, stream>>>(a, b2, 256);

    // 6+7. zs[n] = sum_k whs[k] tanh(Sc[k,n] + Cc@LT) ;
    //      zc[t] = sum_k whc[k] tanh(Cc[k,t] + Sc@L)   (merged via y, K=512)
    a  = {Cc_hi, Cc_lo, 512, PBsc,  LT_hi, LT_lo, 512, PBL,
          Sc_hi, Sc_lo, 512, PBsc,  nullptr, nullptr, 0, 0,
          whs2, zs + (long long)c0 * 512};
    b2 = {Sc_hi, Sc_lo, 512, PBsc,  L_hi, L_lo, 512, PBL,
          Cc_hi, Cc_lo, 512, PBsc,  nullptr, nullptr, 0, 0,
          whc2, zc + (long long)c0 * 512};
    mgemm<2, 2><<<dim3(4, 2, G), blk, 0, stream>>>(a, b2, 512);
  }

  // 8. softmax + attention pooling (f16-hi inputs)
  finalize<<<dim3(128, 2), blk, 0, stream>>>(c_hi, m_hi, zs, zc, out);
}

// Round 7
// 412.526 us; speedup vs baseline: 1.6565x; 1.1005x over previous
//
#include <hip/hip_runtime.h>

typedef _Float16 f16;
typedef __attribute__((ext_vector_type(4))) _Float16 f16x4;
typedef __attribute__((ext_vector_type(8))) _Float16 f16x8;
typedef __attribute__((ext_vector_type(4))) float f32x4;

__device__ __forceinline__ void fsplit(float v, f16& h, f16& l) {
  h = (f16)v;
  l = (f16)(v - (float)h);
}
__device__ __forceinline__ float fast_tanh(float x) {
  float ax = fabsf(x);
  float e = __expf(2.0f * ax);
  float r = 1.0f - 2.0f / (e + 1.0f);
  return copysignf(r, x);
}

#define GLD16(g, l) __builtin_amdgcn_global_load_lds( \
    (const __attribute__((address_space(1))) unsigned int*)(g), \
    (__attribute__((address_space(3))) unsigned int*)(l), 16, 0, 0)

struct GemmArgs {
  const f16* Ah; const f16* Al; int lda; long long sA;
  const f16* Bh; const f16* Bl; int ldb; long long sB;
  f16* Ch; f16* Cl; int ldc; long long sC;
  f16* Th; f16* Tl; int ldt; long long sT;
  const float* wh; float* z;
};

// ---------------------------------------------------------------------------
// Split-fp16 MFMA GEMM: D = A*B^T, A[M][K] hi/lo, B[N][K] hi/lo (both NT).
// 128x128 tile, BK=32, 4 waves (2x2 of 64x64), 4x4 frags of 16x16x32 MFMA.
// 3-product split: AhBh + AhBl + AlBh  (rel err ~2^-23, near-f32).
// K-loop: 2-phase LDS double-buffer (2x32KB), prefetch next tile's
// global_load_lds before compute, ONE __syncthreads per step (its vmcnt(0)
// drain doubles as prefetch-completion wait).
// Epilogues: acc -> f16 hi/lo regs once, then per output plane stage through
// a padded LDS image [128][136] and store f16x8/lane, 256B-contig per row.
// EPI 0: store hi/lo.  EPI 1: tanh -> store hi/lo + transposed hi/lo.
// EPI 2: z[n] = sum_m wh[m]*tanh(acc + bias[m][n]); bias via Ch/Cl.
// NSETS=2: blockIdx.y selects operand set (merged small GEMMs), m0=0.
// ---------------------------------------------------------------------------
template<int EPI, int NSETS>
__global__ __launch_bounds__(256, 2) void mgemm(GemmArgs g0, GemmArgs g1, int Kd)
{
  __shared__ char smem[65536];   // 2 x (4 planes x 8KB) staging; epilogue image
  const GemmArgs& g = (NSETS == 2 && blockIdx.y == 1) ? g1 : g0;
  const int b = blockIdx.z;
  const int m0 = (NSETS == 2) ? 0 : blockIdx.y * 128;
  const int n0 = blockIdx.x * 128;
  const int tid = threadIdx.x;
  const int lane = tid & 63;
  const int wid = tid >> 6;
  const int wrow = (wid >> 1) * 64, wcol = (wid & 1) * 64;
  const int lda = g.lda, ldb = g.ldb;

  const f16* Agh = g.Ah + (long long)b * g.sA;
  const f16* Agl = g.Al + (long long)b * g.sA;
  const f16* Bgh = g.Bh + (long long)b * g.sB;
  const f16* Bgl = g.Bl + (long long)b * g.sB;

  f32x4 acc[4][4];
#pragma unroll
  for (int i = 0; i < 4; ++i)
#pragma unroll
    for (int j = 0; j < 4; ++j) acc[i][j] = f32x4{0.f, 0.f, 0.f, 0.f};

  // staging: thread -> (row = tid>>2 (+64), 16B slot = tid&3); source k-slot
  // pre-swizzled so LDS dest stays linear (tid*16B).
  const int srow = tid >> 2;
  const int sq = tid & 3;
  const int gs0 = ((sq ^ (srow & 3)) * 8);
  const long long gaA0 = (long long)(m0 + srow) * lda + gs0;
  const long long gaA1 = (long long)(m0 + srow + 64) * lda + gs0;
  const long long gaB0 = (long long)(n0 + srow) * ldb + gs0;
  const long long gaB1 = (long long)(n0 + srow + 64) * ldb + gs0;

  auto stage = [&](int k0, int bo) {
    char* pAh = smem + bo;
    char* pAl = smem + bo + 8192;
    char* pBh = smem + bo + 16384;
    char* pBl = smem + bo + 24576;
    GLD16(Agh + gaA0 + k0, pAh + tid * 16);
    GLD16(Agh + gaA1 + k0, pAh + 4096 + tid * 16);
    GLD16(Agl + gaA0 + k0, pAl + tid * 16);
    GLD16(Agl + gaA1 + k0, pAl + 4096 + tid * 16);
    GLD16(Bgh + gaB0 + k0, pBh + tid * 16);
    GLD16(Bgh + gaB1 + k0, pBh + 4096 + tid * 16);
    GLD16(Bgl + gaB0 + k0, pBl + tid * 16);
    GLD16(Bgl + gaB1 + k0, pBl + 4096 + tid * 16);
  };

  // frag read offsets (swizzled slot = kg ^ (row&3)), f16 elements
  const int rl = lane & 15, kg = lane >> 4;
  int aoff[4], boff[4];
#pragma unroll
  for (int i = 0; i < 4; ++i) {
    int rowa = wrow + i * 16 + rl;
    aoff[i] = rowa * 32 + ((kg ^ (rowa & 3)) * 8);
    int rowb = wcol + i * 16 + rl;
    boff[i] = rowb * 32 + ((kg ^ (rowb & 3)) * 8);
  }

  const int nt = Kd >> 5;
  int bufo = 0;
  stage(0, 0);
  __syncthreads();
  for (int t = 0; t < nt; ++t) {
    const int nb = bufo ^ 32768;
    if (t + 1 < nt) stage((t + 1) * 32, nb);   // prefetch overlaps compute

    const f16* sAh = (const f16*)(smem + bufo);
    const f16* sAl = (const f16*)(smem + bufo + 8192);
    const f16* sBh = (const f16*)(smem + bufo + 16384);
    const f16* sBl = (const f16*)(smem + bufo + 24576);
    f16x8 fah[4], fal[4], fbh[4], fbl[4];
#pragma unroll
    for (int i = 0; i < 4; ++i) {
      fah[i] = *(const f16x8*)&sAh[aoff[i]];
      fal[i] = *(const f16x8*)&sAl[aoff[i]];
      fbh[i] = *(const f16x8*)&sBh[boff[i]];
      fbl[i] = *(const f16x8*)&sBl[boff[i]];
    }
#pragma unroll
    for (int i = 0; i < 4; ++i)
#pragma unroll
      for (int j = 0; j < 4; ++j) {
        acc[i][j] = __builtin_amdgcn_mfma_f32_16x16x32_f16(fah[i], fbh[j], acc[i][j], 0, 0, 0);
        acc[i][j] = __builtin_amdgcn_mfma_f32_16x16x32_f16(fah[i], fbl[j], acc[i][j], 0, 0, 0);
        acc[i][j] = __builtin_amdgcn_mfma_f32_16x16x32_f16(fal[i], fbh[j], acc[i][j], 0, 0, 0);
      }
    __syncthreads();   // vmcnt(0) drain = prefetch landed; buffers swap safely
    bufo = nb;
  }

  // C/D layout (measured, m89): col = lane&15, row = (lane>>4)*4 + reg
  if (EPI <= 1) {
    // pack hi/lo f16 planes into registers once
    f16x4 ph[4][4], pl[4][4];
#pragma unroll
    for (int i = 0; i < 4; ++i)
#pragma unroll
      for (int j = 0; j < 4; ++j)
#pragma unroll
        for (int q = 0; q < 4; ++q) {
          float v = (EPI == 1) ? fast_tanh(acc[i][j][q]) : acc[i][j][q];
          f16 h, l; fsplit(v, h, l);
          ph[i][j][q] = h; pl[i][j][q] = l;
        }
    f16* img = (f16*)smem;            // [128][136] padded image
    const int q4 = lane >> 4, c16 = lane & 15;
    const int nplanes = (EPI == 1) ? 4 : 2;
#pragma unroll
    for (int plane = 0; plane < 4; ++plane) {
      if (plane >= nplanes) break;
      const int lo = plane & 1, tr = plane >> 1;
      __syncthreads();                // image free (previous reads done)
      if (!tr) {                      // [row=t][col=n]
#pragma unroll
        for (int i = 0; i < 4; ++i)
#pragma unroll
          for (int j = 0; j < 4; ++j)
#pragma unroll
            for (int q = 0; q < 4; ++q)
              img[(wrow + i * 16 + kg * 4 + q) * 136 + wcol + j * 16 + rl] =
                  lo ? pl[i][j][q] : ph[i][j][q];
      } else {                        // transposed image [row=n][col=t]
#pragma unroll
        for (int i = 0; i < 4; ++i)
#pragma unroll
          for (int j = 0; j < 4; ++j)
            *(f16x4*)&img[(wcol + j * 16 + rl) * 136 + wrow + i * 16 + kg * 4] =
                lo ? pl[i][j] : ph[i][j];
      }
      __syncthreads();
      f16* gb; int grow0, gcol0, ldg;
      if (!tr) { gb = (lo ? g.Cl : g.Ch) + (long long)b * g.sC; grow0 = m0; gcol0 = n0; ldg = g.ldc; }
      else     { gb = (lo ? g.Tl : g.Th) + (long long)b * g.sT; grow0 = n0; gcol0 = m0; ldg = g.ldt; }
#pragma unroll
      for (int it = 0; it < 8; ++it) {
        int r = it * 16 + wid * 4 + q4;
        *(f16x8*)&gb[(long long)(grow0 + r) * ldg + gcol0 + c16 * 8] =
            *(const f16x8*)&img[r * 136 + c16 * 8];
      }
    }
  } else {
    const f16* bh = g.Ch + (long long)b * g.sC;
    const f16* bl = g.Cl + (long long)b * g.sC;
    const int ldc = g.ldc;
    float zp[4] = {0.f, 0.f, 0.f, 0.f};
#pragma unroll
    for (int i = 0; i < 4; ++i)
#pragma unroll
      for (int q = 0; q < 4; ++q) {
        int grow = m0 + wrow + i * 16 + kg * 4 + q;
        float wv = g.wh[grow];
#pragma unroll
        for (int j = 0; j < 4; ++j) {
          int gcol = n0 + wcol + j * 16 + rl;
          long long bi = (long long)grow * ldc + gcol;
          float bias = (float)bh[bi] + (float)bl[bi];
          zp[j] += wv * fast_tanh(acc[i][j][q] + bias);
        }
      }
#pragma unroll
    for (int j = 0; j < 4; ++j) {  // reduce the 4 kg-lanes sharing a column
      zp[j] += __shfl_xor(zp[j], 16);
      zp[j] += __shfl_xor(zp[j], 32);
    }
    __syncthreads();
    float* zred = (float*)smem;
    if (lane < 16) {
#pragma unroll
      for (int j = 0; j < 4; ++j)
        zred[(wid >> 1) * 128 + wcol + j * 16 + lane] = zp[j];
    }
    __syncthreads();
    if (tid < 128)
      g.z[(long long)b * 512 + n0 + tid] = zred[tid] + zred[128 + tid];
  }
}

// ---------------------------------------------------------------------------
__global__ void cvt_hilo2(const float* __restrict__ s0, f16* __restrict__ h0,
                          f16* __restrict__ l0_,
                          const float* __restrict__ s1, f16* __restrict__ h1,
                          f16* __restrict__ l1_, int n4)
{
  const float* src = blockIdx.y ? s1 : s0;
  f16* hi = blockIdx.y ? h1 : h0;
  f16* lo = blockIdx.y ? l1_ : l0_;
  int stride = gridDim.x * blockDim.x;
  for (int i = blockIdx.x * blockDim.x + threadIdx.x; i < n4; i += stride) {
    f32x4 v = ((const f32x4*)src)[i];
    f16x4 h, l;
#pragma unroll
    for (int c = 0; c < 4; ++c) {
      f16 hh, ll;
      fsplit(v[c], hh, ll);
      h[c] = hh; l[c] = ll;
    }
    ((f16x4*)hi)[i] = h;
    ((f16x4*)lo)[i] = l;
  }
}

__global__ void prep_weights(const float* __restrict__ Wl, const float* __restrict__ Ws,
                             const float* __restrict__ Wc, const float* __restrict__ whs,
                             const float* __restrict__ whc,
                             f16* __restrict__ WlT_hi, f16* __restrict__ WlT_lo,
                             f16* __restrict__ Ws2_hi, f16* __restrict__ Ws2_lo,
                             f16* __restrict__ Wc2_hi, f16* __restrict__ Wc2_lo,
                             float* __restrict__ whs2, float* __restrict__ whc2)
{
  const int blk = blockIdx.x, t = threadIdx.x;
  if (blk < 256) {            // WlT[D][d] = Wl[d][D]
    f16 h, l;
    fsplit(Wl[t * 256 + blk], h, l);
    WlT_hi[blk * 256 + t] = h;
    WlT_lo[blk * 256 + t] = l;
  } else if (blk < 384) {     // Ws padded K 80->128
    int k = blk - 256;
    f16 h, l;
    fsplit((k < 80) ? Ws[k * 256 + t] : 0.f, h, l);
    Ws2_hi[k * 256 + t] = h;
    Ws2_lo[k * 256 + t] = l;
  } else if (blk < 512) {     // Wc padded
    int k = blk - 384;
    f16 h, l;
    fsplit((k < 80) ? Wc[k * 256 + t] : 0.f, h, l);
    Wc2_hi[k * 256 + t] = h;
    Wc2_lo[k * 256 + t] = l;
  } else {
    if (t < 128) whs2[t] = (t < 80) ? whs[t] : 0.f;
    else { int k = t - 128; whc2[k] = (k < 80) ? whc[k] : 0.f; }
  }
}

__global__ __launch_bounds__(256) void finalize(
    const float* __restrict__ content, const float* __restrict__ comments,
    const float* __restrict__ zs, const float* __restrict__ zc,
    float* __restrict__ out)
{
  const int b = blockIdx.x;
  const int half = blockIdx.y;
  const int tid = threadIdx.x;
  __shared__ float w[512];
  __shared__ float red[256];
  const float* z = (half ? zc : zs) + b * 512;
  const float* X = (half ? comments : content) + (long long)b * 512 * 256;
  float v0 = z[tid], v1 = z[tid + 256];
  red[tid] = fmaxf(v0, v1);
  __syncthreads();
  for (int s = 128; s > 0; s >>= 1) {
    if (tid < s) red[tid] = fmaxf(red[tid], red[tid + s]);
    __syncthreads();
  }
  float mx = red[0];
  __syncthreads();
  float e0 = __expf(v0 - mx), e1 = __expf(v1 - mx);
  red[tid] = e0 + e1;
  __syncthreads();
  for (int s = 128; s > 0; s >>= 1) {
    if (tid < s) red[tid] += red[tid + s];
    __syncthreads();
  }
  float inv = 1.0f / red[0];
  w[tid] = e0 * inv;
  w[tid + 256] = e1 * inv;
  __syncthreads();
  float acc2 = 0.f;
  for (int r = 0; r < 512; ++r)
    acc2 = fmaf(w[r], X[(long long)r * 256 + tid], acc2);
  out[(long long)b * 512 + half * 256 + tid] = acc2;
}

// ---------------------------------------------------------------------------
extern "C" void kernel_launch(void* const* d_in, const int* in_sizes, int n_in,
                              void* d_out, int out_size, void* d_ws, size_t ws_size,
                              hipStream_t stream) {
  (void)in_sizes; (void)n_in; (void)out_size;
  const float* content  = (const float*)d_in[0];
  const float* comments = (const float*)d_in[1];
  const float* Wl  = (const float*)d_in[2];
  const float* Wc  = (const float*)d_in[3];
  const float* Ws  = (const float*)d_in[4];
  const float* whs = (const float*)d_in[5];
  const float* whc = (const float*)d_in[6];
  float* out = (float*)d_out;

  const long long PBcm = 512 * 256;   // per-batch elems, content/comments
  const long long PBL  = 512 * 512;   // per-batch elems, L / LT
  const long long PBsc = 128 * 512;   // per-batch elems, Sc / Cc

  // per-batch chunked ws: c/m 4 planes (1 MiB) + CW(=Sc/Cc alias) 0.5 MiB
  //                       + L 1 MiB + LT 1 MiB = 3.5 MiB; fixed ~1.2 MiB.
  const size_t perG = 3670016;   // 3.5 MiB
  int G = 16;
  if      (ws_size >= 64 * perG + (4ULL << 20)) G = 64;
  else if (ws_size >= 32 * perG + (4ULL << 20)) G = 32;

  char* base = (char*)d_ws;
  size_t off = 0;
  auto alloc = [&](size_t bytes) -> char* {
    char* p = base + off;
    off = (off + bytes + 255) & ~(size_t)255;
    return p;
  };

  // chunked planes
  f16* c_hi  = (f16*)alloc((size_t)G * PBcm * 2);
  f16* c_lo  = (f16*)alloc((size_t)G * PBcm * 2);
  f16* m_hi  = (f16*)alloc((size_t)G * PBcm * 2);
  f16* m_lo  = (f16*)alloc((size_t)G * PBcm * 2);
  f16* CW_hi = (f16*)alloc((size_t)G * PBcm * 2);
  f16* CW_lo = (f16*)alloc((size_t)G * PBcm * 2);
  f16* L_hi  = (f16*)alloc((size_t)G * PBL * 2);
  f16* L_lo  = (f16*)alloc((size_t)G * PBL * 2);
  f16* LT_hi = (f16*)alloc((size_t)G * PBL * 2);
  f16* LT_lo = (f16*)alloc((size_t)G * PBL * 2);
  // Sc/Cc alias the CW region (CW dead after step 3; 4*G*PBsc == 2*G*PBcm)
  f16* Sc_hi = CW_hi;
  f16* Sc_lo = Sc_hi + (size_t)G * PBsc;
  f16* Cc_hi = Sc_lo + (size_t)G * PBsc;
  f16* Cc_lo = Cc_hi + (size_t)G * PBsc;
  // fixed
  f16* WlT_hi = (f16*)alloc(256 * 256 * 2);
  f16* WlT_lo = (f16*)alloc(256 * 256 * 2);
  f16* Ws2_hi = (f16*)alloc(128 * 256 * 2);
  f16* Ws2_lo = (f16*)alloc(128 * 256 * 2);
  f16* Wc2_hi = (f16*)alloc(128 * 256 * 2);
  f16* Wc2_lo = (f16*)alloc(128 * 256 * 2);
  float* whs2 = (float*)alloc(512);
  float* whc2 = (float*)alloc(512);
  float* zs = (float*)alloc(128 * 512 * 4);
  float* zc = (float*)alloc(128 * 512 * 4);

  dim3 blk(256);

  prep_weights<<<dim3(513), blk, 0, stream>>>(Wl, Ws, Wc, whs, whc,
      WlT_hi, WlT_lo, Ws2_hi, Ws2_lo, Wc2_hi, Wc2_lo, whs2, whc2);

  for (int c0 = 0; c0 < 128; c0 += G) {
    // 1. convert this chunk's inputs to hi/lo f16
    cvt_hilo2<<<dim3(1024, 2), blk, 0, stream>>>(
        content + (long long)c0 * PBcm, c_hi, c_lo,
        comments + (long long)c0 * PBcm, m_hi, m_lo,
        (int)((long long)G * PBcm / 4));

    GemmArgs a, b2;

    // 2. CW = comments @ Wl   (M=512, N=256, K=256)
    a = {m_hi, m_lo, 256, PBcm,  WlT_hi, WlT_lo, 256, 0,
         CW_hi, CW_lo, 256, PBcm,  nullptr, nullptr, 0, 0,  nullptr, nullptr};
    mgemm<0, 1><<<dim3(2, 4, G), blk, 0, stream>>>(a, a, 256);

    // 3. L = tanh(CW @ content^T) -> L[t][n] + LT[n][t], hi/lo
    a = {CW_hi, CW_lo, 256, PBcm,  c_hi, c_lo, 256, PBcm,
         L_hi, L_lo, 512, PBL,  LT_hi, LT_lo, 512, PBL,  nullptr, nullptr};
    mgemm<1, 1><<<dim3(4, 4, G), blk, 0, stream>>>(a, a, 256);

    // 4+5. Sc = Ws2 @ content^T ; Cc = Wc2 @ comments^T  (merged via y)
    //      (writes alias the dead CW region)
    a  = {Ws2_hi, Ws2_lo, 256, 0,  c_hi, c_lo, 256, PBcm,
          Sc_hi, Sc_lo, 512, PBsc,  nullptr, nullptr, 0, 0,  nullptr, nullptr};
    b2 = {Wc2_hi, Wc2_lo, 256, 0,  m_hi, m_lo, 256, PBcm,
          Cc_hi, Cc_lo, 512, PBsc,  nullptr, nullptr, 0, 0,  nullptr, nullptr};
    mgemm<0, 2><<<dim3(4, 2, G), blk, 0, stream>>>(a, b2, 256);

    // 6+7. zs[n] = sum_k whs[k] tanh(Sc[k,n] + Cc@LT) ;
    //      zc[t] = sum_k whc[k] tanh(Cc[k,t] + Sc@L)   (merged via y, K=512)
    a  = {Cc_hi, Cc_lo, 512, PBsc,  LT_hi, LT_lo, 512, PBL,
          Sc_hi, Sc_lo, 512, PBsc,  nullptr, nullptr, 0, 0,
          whs2, zs + (long long)c0 * 512};
    b2 = {Sc_hi, Sc_lo, 512, PBsc,  L_hi, L_lo, 512, PBL,
          Cc_hi, Cc_lo, 512, PBsc,  nullptr, nullptr, 0, 0,
          whc2, zc + (long long)c0 * 512};
    mgemm<2, 2><<<dim3(4, 2, G), blk, 0, stream>>>(a, b2, 512);
  }

  // 8. softmax + attention pooling (original f32 inputs)
  finalize<<<dim3(128, 2), blk, 0, stream>>>(content, comments, zs, zc, out);
}

// Round 9
// 344.050 us; speedup vs baseline: 1.9861x; 1.1990x over previous
//
#include <hip/hip_runtime.h>

typedef _Float16 f16;
typedef __attribute__((ext_vector_type(4))) _Float16 f16x4;
typedef __attribute__((ext_vector_type(8))) _Float16 f16x8;
typedef __attribute__((ext_vector_type(4))) float f32x4;

__device__ __forceinline__ void fsplit(float v, f16& h, f16& l) {
  h = (f16)v;
  l = (f16)(v - (float)h);
}
__device__ __forceinline__ float fast_tanh(float x) {
  float ax = fabsf(x);
  float e = __expf(2.0f * ax);
  float r = 1.0f - 2.0f / (e + 1.0f);
  return copysignf(r, x);
}

#define GLD16(g, l) __builtin_amdgcn_global_load_lds( \
    (const __attribute__((address_space(1))) unsigned int*)(g), \
    (__attribute__((address_space(3))) unsigned int*)(l), 16, 0, 0)

// XCD-aware block swizzle: each XCD gets a contiguous range of virtual tiles
// (consecutive virt share A-panels -> L2 hits). Bijective: all grids % 8 == 0.
__device__ __forceinline__ void xcd_swz(int& bx, int& by, int& bz) {
  const int gx = gridDim.x, gy = gridDim.y;
  const int nwg = gx * gy * gridDim.z;
  const int flat = blockIdx.x + gx * (blockIdx.y + gy * blockIdx.z);
  const int virt = (flat & 7) * (nwg >> 3) + (flat >> 3);
  bx = virt % gx;
  const int rest = virt / gx;
  by = rest % gy;
  bz = rest / gy;
}

struct GemmArgs {
  const f16* Ah; const f16* Al; int lda; long long sA;
  const f16* Bh; const f16* Bl; int ldb; long long sB;
  f16* Ch; f16* Cl; int ldc; long long sC;
  f16* Th; f16* Tl; int ldt; long long sT;
  const float* wh; float* z;
};

// ---------------------------------------------------------------------------
// Split-fp16 MFMA GEMM: D = A*B^T, A[M][K] hi/lo, B[N][K] hi/lo (both NT).
// 128x128 tile, BK=32, 4 waves (2x2 of 64x64), 4x4 frags of 16x16x32 MFMA.
// 3-product split: AhBh + AhBl + AlBh  (rel err ~2^-23, near-f32).
// K-loop: 2-phase LDS double-buffer (2x32KB), prefetch next tile's
// global_load_lds before compute, ONE __syncthreads per step (its vmcnt(0)
// drain doubles as prefetch-completion wait).
// Epilogues: acc -> f16 hi/lo regs once, then per output plane stage through
// a padded LDS image [128][136] and store f16x8/lane, 256B-contig per row.
// EPI 0: store hi/lo.  EPI 1: tanh -> store hi/lo + transposed hi/lo.
// EPI 2: z[n] = sum_m wh[m]*tanh(acc + bias[m][n]); bias via Ch/Cl.
// NSETS=2: by selects operand set (merged small GEMMs), m0=0.
// ---------------------------------------------------------------------------
template<int EPI, int NSETS>
__global__ __launch_bounds__(256, 2) void mgemm(GemmArgs g0, GemmArgs g1, int Kd)
{
  __shared__ char smem[65536];   // 2 x (4 planes x 8KB) staging; epilogue image
  int bx, by, bz;
  xcd_swz(bx, by, bz);
  const GemmArgs& g = (NSETS == 2 && by == 1) ? g1 : g0;
  const int b = bz;
  const int m0 = (NSETS == 2) ? 0 : by * 128;
  const int n0 = bx * 128;
  const int tid = threadIdx.x;
  const int lane = tid & 63;
  const int wid = tid >> 6;
  const int wrow = (wid >> 1) * 64, wcol = (wid & 1) * 64;
  const int lda = g.lda, ldb = g.ldb;

  const f16* Agh = g.Ah + (long long)b * g.sA;
  const f16* Agl = g.Al + (long long)b * g.sA;
  const f16* Bgh = g.Bh + (long long)b * g.sB;
  const f16* Bgl = g.Bl + (long long)b * g.sB;

  f32x4 acc[4][4];
#pragma unroll
  for (int i = 0; i < 4; ++i)
#pragma unroll
    for (int j = 0; j < 4; ++j) acc[i][j] = f32x4{0.f, 0.f, 0.f, 0.f};

  // staging: thread -> (row = tid>>2 (+64), 16B slot = tid&3); source k-slot
  // pre-swizzled so LDS dest stays linear (tid*16B).
  const int srow = tid >> 2;
  const int sq = tid & 3;
  const int gs0 = ((sq ^ (srow & 3)) * 8);
  const long long gaA0 = (long long)(m0 + srow) * lda + gs0;
  const long long gaA1 = (long long)(m0 + srow + 64) * lda + gs0;
  const long long gaB0 = (long long)(n0 + srow) * ldb + gs0;
  const long long gaB1 = (long long)(n0 + srow + 64) * ldb + gs0;

  auto stage = [&](int k0, int bo) {
    char* pAh = smem + bo;
    char* pAl = smem + bo + 8192;
    char* pBh = smem + bo + 16384;
    char* pBl = smem + bo + 24576;
    GLD16(Agh + gaA0 + k0, pAh + tid * 16);
    GLD16(Agh + gaA1 + k0, pAh + 4096 + tid * 16);
    GLD16(Agl + gaA0 + k0, pAl + tid * 16);
    GLD16(Agl + gaA1 + k0, pAl + 4096 + tid * 16);
    GLD16(Bgh + gaB0 + k0, pBh + tid * 16);
    GLD16(Bgh + gaB1 + k0, pBh + 4096 + tid * 16);
    GLD16(Bgl + gaB0 + k0, pBl + tid * 16);
    GLD16(Bgl + gaB1 + k0, pBl + 4096 + tid * 16);
  };

  // frag read offsets (swizzled slot = kg ^ (row&3)), f16 elements
  const int rl = lane & 15, kg = lane >> 4;
  int aoff[4], boff[4];
#pragma unroll
  for (int i = 0; i < 4; ++i) {
    int rowa = wrow + i * 16 + rl;
    aoff[i] = rowa * 32 + ((kg ^ (rowa & 3)) * 8);
    int rowb = wcol + i * 16 + rl;
    boff[i] = rowb * 32 + ((kg ^ (rowb & 3)) * 8);
  }

  const int nt = Kd >> 5;
  int bufo = 0;
  stage(0, 0);
  __syncthreads();
  for (int t = 0; t < nt; ++t) {
    const int nb = bufo ^ 32768;
    if (t + 1 < nt) stage((t + 1) * 32, nb);   // prefetch overlaps compute

    const f16* sAh = (const f16*)(smem + bufo);
    const f16* sAl = (const f16*)(smem + bufo + 8192);
    const f16* sBh = (const f16*)(smem + bufo + 16384);
    const f16* sBl = (const f16*)(smem + bufo + 24576);
    f16x8 fah[4], fal[4], fbh[4], fbl[4];
#pragma unroll
    for (int i = 0; i < 4; ++i) {
      fah[i] = *(const f16x8*)&sAh[aoff[i]];
      fal[i] = *(const f16x8*)&sAl[aoff[i]];
      fbh[i] = *(const f16x8*)&sBh[boff[i]];
      fbl[i] = *(const f16x8*)&sBl[boff[i]];
    }
#pragma unroll
    for (int i = 0; i < 4; ++i)
#pragma unroll
      for (int j = 0; j < 4; ++j) {
        acc[i][j] = __builtin_amdgcn_mfma_f32_16x16x32_f16(fah[i], fbh[j], acc[i][j], 0, 0, 0);
        acc[i][j] = __builtin_amdgcn_mfma_f32_16x16x32_f16(fah[i], fbl[j], acc[i][j], 0, 0, 0);
        acc[i][j] = __builtin_amdgcn_mfma_f32_16x16x32_f16(fal[i], fbh[j], acc[i][j], 0, 0, 0);
      }
    __syncthreads();   // vmcnt(0) drain = prefetch landed; buffers swap safely
    bufo = nb;
  }

  // C/D layout (measured, m89): col = lane&15, row = (lane>>4)*4 + reg
  if (EPI <= 1) {
    // pack hi/lo f16 planes into registers once
    f16x4 ph[4][4], pl[4][4];
#pragma unroll
    for (int i = 0; i < 4; ++i)
#pragma unroll
      for (int j = 0; j < 4; ++j)
#pragma unroll
        for (int q = 0; q < 4; ++q) {
          float v = (EPI == 1) ? fast_tanh(acc[i][j][q]) : acc[i][j][q];
          f16 h, l; fsplit(v, h, l);
          ph[i][j][q] = h; pl[i][j][q] = l;
        }
    f16* img = (f16*)smem;            // [128][136] padded image
    const int q4 = lane >> 4, c16 = lane & 15;
    const int nplanes = (EPI == 1) ? 4 : 2;
#pragma unroll
    for (int plane = 0; plane < 4; ++plane) {
      if (plane >= nplanes) break;
      const int lo = plane & 1, tr = plane >> 1;
      __syncthreads();                // image free (previous reads done)
      if (!tr) {                      // [row=t][col=n]
#pragma unroll
        for (int i = 0; i < 4; ++i)
#pragma unroll
          for (int j = 0; j < 4; ++j)
#pragma unroll
            for (int q = 0; q < 4; ++q)
              img[(wrow + i * 16 + kg * 4 + q) * 136 + wcol + j * 16 + rl] =
                  lo ? pl[i][j][q] : ph[i][j][q];
      } else {                        // transposed image [row=n][col=t]
#pragma unroll
        for (int i = 0; i < 4; ++i)
#pragma unroll
          for (int j = 0; j < 4; ++j)
            *(f16x4*)&img[(wcol + j * 16 + rl) * 136 + wrow + i * 16 + kg * 4] =
                lo ? pl[i][j] : ph[i][j];
      }
      __syncthreads();
      f16* gb; int grow0, gcol0, ldg;
      if (!tr) { gb = (lo ? g.Cl : g.Ch) + (long long)b * g.sC; grow0 = m0; gcol0 = n0; ldg = g.ldc; }
      else     { gb = (lo ? g.Tl : g.Th) + (long long)b * g.sT; grow0 = n0; gcol0 = m0; ldg = g.ldt; }
#pragma unroll
      for (int it = 0; it < 8; ++it) {
        int r = it * 16 + wid * 4 + q4;
        *(f16x8*)&gb[(long long)(grow0 + r) * ldg + gcol0 + c16 * 8] =
            *(const f16x8*)&img[r * 136 + c16 * 8];
      }
    }
  } else {
    const f16* bh = g.Ch + (long long)b * g.sC;
    const f16* bl = g.Cl + (long long)b * g.sC;
    const int ldc = g.ldc;
    float zp[4] = {0.f, 0.f, 0.f, 0.f};
#pragma unroll
    for (int i = 0; i < 4; ++i)
#pragma unroll
      for (int q = 0; q < 4; ++q) {
        int grow = m0 + wrow + i * 16 + kg * 4 + q;
        float wv = g.wh[grow];
#pragma unroll
        for (int j = 0; j < 4; ++j) {
          int gcol = n0 + wcol + j * 16 + rl;
          long long bi = (long long)grow * ldc + gcol;
          float bias = (float)bh[bi] + (float)bl[bi];
          zp[j] += wv * fast_tanh(acc[i][j][q] + bias);
        }
      }
#pragma unroll
    for (int j = 0; j < 4; ++j) {  // reduce the 4 kg-lanes sharing a column
      zp[j] += __shfl_xor(zp[j], 16);
      zp[j] += __shfl_xor(zp[j], 32);
    }
    __syncthreads();
    float* zred = (float*)smem;
    if (lane < 16) {
#pragma unroll
      for (int j = 0; j < 4; ++j)
        zred[(wid >> 1) * 128 + wcol + j * 16 + lane] = zp[j];
    }
    __syncthreads();
    if (tid < 128)
      g.z[(long long)b * 512 + n0 + tid] = zred[tid] + zred[128 + tid];
  }
}

// ---------------------------------------------------------------------------
__global__ void cvt_hilo2(const float* __restrict__ s0, f16* __restrict__ h0,
                          f16* __restrict__ l0_,
                          const float* __restrict__ s1, f16* __restrict__ h1,
                          f16* __restrict__ l1_, int n4)
{
  const float* src = blockIdx.y ? s1 : s0;
  f16* hi = blockIdx.y ? h1 : h0;
  f16* lo = blockIdx.y ? l1_ : l0_;
  int stride = gridDim.x * blockDim.x;
  for (int i = blockIdx.x * blockDim.x + threadIdx.x; i < n4; i += stride) {
    f32x4 v = ((const f32x4*)src)[i];
    f16x4 h, l;
#pragma unroll
    for (int c = 0; c < 4; ++c) {
      f16 hh, ll;
      fsplit(v[c], hh, ll);
      h[c] = hh; l[c] = ll;
    }
    ((f16x4*)hi)[i] = h;
    ((f16x4*)lo)[i] = l;
  }
}

__global__ void prep_weights(const float* __restrict__ Wl, const float* __restrict__ Ws,
                             const float* __restrict__ Wc, const float* __restrict__ whs,
                             const float* __restrict__ whc,
                             f16* __restrict__ WlT_hi, f16* __restrict__ WlT_lo,
                             f16* __restrict__ Ws2_hi, f16* __restrict__ Ws2_lo,
                             f16* __restrict__ Wc2_hi, f16* __restrict__ Wc2_lo,
                             float* __restrict__ whs2, float* __restrict__ whc2)
{
  const int blk = blockIdx.x, t = threadIdx.x;
  if (blk < 256) {            // WlT[D][d] = Wl[d][D]
    f16 h, l;
    fsplit(Wl[t * 256 + blk], h, l);
    WlT_hi[blk * 256 + t] = h;
    WlT_lo[blk * 256 + t] = l;
  } else if (blk < 384) {     // Ws padded K 80->128
    int k = blk - 256;
    f16 h, l;
    fsplit((k < 80) ? Ws[k * 256 + t] : 0.f, h, l);
    Ws2_hi[k * 256 + t] = h;
    Ws2_lo[k * 256 + t] = l;
  } else if (blk < 512) {     // Wc padded
    int k = blk - 384;
    f16 h, l;
    fsplit((k < 80) ? Wc[k * 256 + t] : 0.f, h, l);
    Wc2_hi[k * 256 + t] = h;
    Wc2_lo[k * 256 + t] = l;
  } else {
    if (t < 128) whs2[t] = (t < 80) ? whs[t] : 0.f;
    else { int k = t - 128; whc2[k] = (k < 80) ? whc[k] : 0.f; }
  }
}

__global__ __launch_bounds__(256) void finalize(
    const float* __restrict__ content, const float* __restrict__ comments,
    const float* __restrict__ zs, const float* __restrict__ zc,
    float* __restrict__ out)
{
  const int b = blockIdx.x;
  const int half = blockIdx.y;
  const int tid = threadIdx.x;
  __shared__ float w[512];
  __shared__ float red[256];
  const float* z = (half ? zc : zs) + b * 512;
  const float* X = (half ? comments : content) + (long long)b * 512 * 256;
  float v0 = z[tid], v1 = z[tid + 256];
  red[tid] = fmaxf(v0, v1);
  __syncthreads();
  for (int s = 128; s > 0; s >>= 1) {
    if (tid < s) red[tid] = fmaxf(red[tid], red[tid + s]);
    __syncthreads();
  }
  float mx = red[0];
  __syncthreads();
  float e0 = __expf(v0 - mx), e1 = __expf(v1 - mx);
  red[tid] = e0 + e1;
  __syncthreads();
  for (int s = 128; s > 0; s >>= 1) {
    if (tid < s) red[tid] += red[tid + s];
    __syncthreads();
  }
  float inv = 1.0f / red[0];
  w[tid] = e0 * inv;
  w[tid + 256] = e1 * inv;
  __syncthreads();
  float acc2 = 0.f;
  for (int r = 0; r < 512; ++r)
    acc2 = fmaf(w[r], X[(long long)r * 256 + tid], acc2);
  out[(long long)b * 512 + half * 256 + tid] = acc2;
}

// ---------------------------------------------------------------------------
extern "C" void kernel_launch(void* const* d_in, const int* in_sizes, int n_in,
                              void* d_out, int out_size, void* d_ws, size_t ws_size,
                              hipStream_t stream) {
  (void)in_sizes; (void)n_in; (void)out_size;
  const float* content  = (const float*)d_in[0];
  const float* comments = (const float*)d_in[1];
  const float* Wl  = (const float*)d_in[2];
  const float* Wc  = (const float*)d_in[3];
  const float* Ws  = (const float*)d_in[4];
  const float* whs = (const float*)d_in[5];
  const float* whc = (const float*)d_in[6];
  float* out = (float*)d_out;

  const long long PBcm = 512 * 256;   // per-batch elems, content/comments
  const long long PBL  = 512 * 512;   // per-batch elems, L / LT
  const long long PBsc = 128 * 512;   // per-batch elems, Sc / Cc

  // per-batch chunked ws: c/m 4 planes (1 MiB) + CW(=Sc/Cc alias) 0.5 MiB
  //                       + L 1 MiB + LT 1 MiB = 3.5 MiB; fixed ~1.2 MiB.
  const size_t perG = 3670016;   // 3.5 MiB
  int G = 16;
  if      (ws_size >= 64 * perG + (4ULL << 20)) G = 64;
  else if (ws_size >= 32 * perG + (4ULL << 20)) G = 32;

  char* base = (char*)d_ws;
  size_t off = 0;
  auto alloc = [&](size_t bytes) -> char* {
    char* p = base + off;
    off = (off + bytes + 255) & ~(size_t)255;
    return p;
  };

  // chunked planes
  f16* c_hi  = (f16*)alloc((size_t)G * PBcm * 2);
  f16* c_lo  = (f16*)alloc((size_t)G * PBcm * 2);
  f16* m_hi  = (f16*)alloc((size_t)G * PBcm * 2);
  f16* m_lo  = (f16*)alloc((size_t)G * PBcm * 2);
  f16* CW_hi = (f16*)alloc((size_t)G * PBcm * 2);
  f16* CW_lo = (f16*)alloc((size_t)G * PBcm * 2);
  f16* L_hi  = (f16*)alloc((size_t)G * PBL * 2);
  f16* L_lo  = (f16*)alloc((size_t)G * PBL * 2);
  f16* LT_hi = (f16*)alloc((size_t)G * PBL * 2);
  f16* LT_lo = (f16*)alloc((size_t)G * PBL * 2);
  // Sc/Cc alias the CW region (CW dead after step 3; 4*G*PBsc == 2*G*PBcm)
  f16* Sc_hi = CW_hi;
  f16* Sc_lo = Sc_hi + (size_t)G * PBsc;
  f16* Cc_hi = Sc_lo + (size_t)G * PBsc;
  f16* Cc_lo = Cc_hi + (size_t)G * PBsc;
  // fixed
  f16* WlT_hi = (f16*)alloc(256 * 256 * 2);
  f16* WlT_lo = (f16*)alloc(256 * 256 * 2);
  f16* Ws2_hi = (f16*)alloc(128 * 256 * 2);
  f16* Ws2_lo = (f16*)alloc(128 * 256 * 2);
  f16* Wc2_hi = (f16*)alloc(128 * 256 * 2);
  f16* Wc2_lo = (f16*)alloc(128 * 256 * 2);
  float* whs2 = (float*)alloc(512);
  float* whc2 = (float*)alloc(512);
  float* zs = (float*)alloc(128 * 512 * 4);
  float* zc = (float*)alloc(128 * 512 * 4);

  dim3 blk(256);

  prep_weights<<<dim3(513), blk, 0, stream>>>(Wl, Ws, Wc, whs, whc,
      WlT_hi, WlT_lo, Ws2_hi, Ws2_lo, Wc2_hi, Wc2_lo, whs2, whc2);

  for (int c0 = 0; c0 < 128; c0 += G) {
    // 1. convert this chunk's inputs to hi/lo f16
    cvt_hilo2<<<dim3(1024, 2), blk, 0, stream>>>(
        content + (long long)c0 * PBcm, c_hi, c_lo,
        comments + (long long)c0 * PBcm, m_hi, m_lo,
        (int)((long long)G * PBcm / 4));

    GemmArgs a, b2;

    // 2. CW = comments @ Wl   (M=512, N=256, K=256)
    a = {m_hi, m_lo, 256, PBcm,  WlT_hi, WlT_lo, 256, 0,
         CW_hi, CW_lo, 256, PBcm,  nullptr, nullptr, 0, 0,  nullptr, nullptr};
    mgemm<0, 1><<<dim3(2, 4, G), blk, 0, stream>>>(a, a, 256);

    // 3. L = tanh(CW @ content^T) -> L[t][n] + LT[n][t], hi/lo
    a = {CW_hi, CW_lo, 256, PBcm,  c_hi, c_lo, 256, PBcm,
         L_hi, L_lo, 512, PBL,  LT_hi, LT_lo, 512, PBL,  nullptr, nullptr};
    mgemm<1, 1><<<dim3(4, 4, G), blk, 0, stream>>>(a, a, 256);

    // 4+5. Sc = Ws2 @ content^T ; Cc = Wc2 @ comments^T  (merged via y;
    //      writes alias the dead CW region)
    a  = {Ws2_hi, Ws2_lo, 256, 0,  c_hi, c_lo, 256, PBcm,
          Sc_hi, Sc_lo, 512, PBsc,  nullptr, nullptr, 0, 0,  nullptr, nullptr};
    b2 = {Wc2_hi, Wc2_lo, 256, 0,  m_hi, m_lo, 256, PBcm,
          Cc_hi, Cc_lo, 512, PBsc,  nullptr, nullptr, 0, 0,  nullptr, nullptr};
    mgemm<0, 2><<<dim3(4, 2, G), blk, 0, stream>>>(a, b2, 256);

    // 6+7. zs[n] = sum_k whs[k] tanh(Sc[k,n] + Cc@LT) ;
    //      zc[t] = sum_k whc[k] tanh(Cc[k,t] + Sc@L)   (merged via y, K=512)
    a  = {Cc_hi, Cc_lo, 512, PBsc,  LT_hi, LT_lo, 512, PBL,
          Sc_hi, Sc_lo, 512, PBsc,  nullptr, nullptr, 0, 0,
          whs2, zs + (long long)c0 * 512};
    b2 = {Sc_hi, Sc_lo, 512, PBsc,  L_hi, L_lo, 512, PBL,
          Cc_hi, Cc_lo, 512, PBsc,  nullptr, nullptr, 0, 0,
          whc2, zc + (long long)c0 * 512};
    mgemm<2, 2><<<dim3(4, 2, G), blk, 0, stream>>>(a, b2, 512);
  }

  // 8. softmax + attention pooling (original f32 inputs)
  finalize<<<dim3(128, 2), blk, 0, stream>>>(content, comments, zs, zc, out);
}

// Round 10
// 332.977 us; speedup vs baseline: 2.0522x; 1.0333x over previous
//
#include <hip/hip_runtime.h>

typedef _Float16 f16;
typedef __attribute__((ext_vector_type(4))) _Float16 f16x4;
typedef __attribute__((ext_vector_type(8))) _Float16 f16x8;
typedef __attribute__((ext_vector_type(4))) float f32x4;

__device__ __forceinline__ void fsplit(float v, f16& h, f16& l) {
  h = (f16)v;
  l = (f16)(v - (float)h);
}
__device__ __forceinline__ float fast_tanh(float x) {
  float ax = fabsf(x);
  float e = __expf(2.0f * ax);
  float r = 1.0f - 2.0f / (e + 1.0f);
  return copysignf(r, x);
}

#define GLD16(g, l) __builtin_amdgcn_global_load_lds( \
    (const __attribute__((address_space(1))) unsigned int*)(g), \
    (__attribute__((address_space(3))) unsigned int*)(l), 16, 0, 0)

// XCD-aware block swizzle: each XCD gets a contiguous range of virtual tiles
// (consecutive virt share A-panels -> L2 hits). Bijective: all grids % 8 == 0.
__device__ __forceinline__ void xcd_swz(int& bx, int& by, int& bz) {
  const int gx = gridDim.x, gy = gridDim.y;
  const int nwg = gx * gy * gridDim.z;
  const int flat = blockIdx.x + gx * (blockIdx.y + gy * blockIdx.z);
  const int virt = (flat & 7) * (nwg >> 3) + (flat >> 3);
  bx = virt % gx;
  const int rest = virt / gx;
  by = rest % gy;
  bz = rest / gy;
}

struct GemmArgs {
  const f16* Ah; const f16* Al; int lda; long long sA;
  const f16* Bh; const f16* Bl; int ldb; long long sB;
  f16* Ch; f16* Cl; int ldc; long long sC;
  f16* Th; f16* Tl; int ldt; long long sT;
  const float* wh; float* z;
};

// ---------------------------------------------------------------------------
// Split-fp16 MFMA GEMM: D = A*B^T, A[M][K] hi/lo, B[N][K] hi/lo (both NT).
// 128x128 tile, BK=32, 4 waves (2x2 of 64x64), 4x4 frags of 16x16x32 MFMA.
// 3-product split: AhBh + AhBl + AlBh  (rel err ~2^-23, near-f32).
// K-loop: 2-phase LDS double-buffer (2x32KB), prefetch next tile's
// global_load_lds before compute, ONE __syncthreads per step (its vmcnt(0)
// drain doubles as prefetch-completion wait).
// Epilogues: acc -> f16 hi/lo regs once, then per output plane stage through
// a padded LDS image [128][136] and store f16x8/lane, 256B-contig per row.
// EPI 0: store hi/lo.  EPI 1: tanh -> store hi/lo + transposed hi/lo.
// EPI 2: z[n] = sum_m wh[m]*tanh(acc + bias[m][n]); bias via Ch/Cl.
// NSETS=2: by selects operand set (merged small GEMMs), m0=0.
// ---------------------------------------------------------------------------
template<int EPI, int NSETS>
__global__ __launch_bounds__(256, 2) void mgemm(GemmArgs g0, GemmArgs g1, int Kd)
{
  __shared__ char smem[65536];   // 2 x (4 planes x 8KB) staging; epilogue image
  int bx, by, bz;
  xcd_swz(bx, by, bz);
  const GemmArgs& g = (NSETS == 2 && by == 1) ? g1 : g0;
  const int b = bz;
  const int m0 = (NSETS == 2) ? 0 : by * 128;
  const int n0 = bx * 128;
  const int tid = threadIdx.x;
  const int lane = tid & 63;
  const int wid = tid >> 6;
  const int wrow = (wid >> 1) * 64, wcol = (wid & 1) * 64;
  const int lda = g.lda, ldb = g.ldb;

  const f16* Agh = g.Ah + (long long)b * g.sA;
  const f16* Agl = g.Al + (long long)b * g.sA;
  const f16* Bgh = g.Bh + (long long)b * g.sB;
  const f16* Bgl = g.Bl + (long long)b * g.sB;

  f32x4 acc[4][4];
#pragma unroll
  for (int i = 0; i < 4; ++i)
#pragma unroll
    for (int j = 0; j < 4; ++j) acc[i][j] = f32x4{0.f, 0.f, 0.f, 0.f};

  // staging: thread -> (row = tid>>2 (+64), 16B slot = tid&3); source k-slot
  // pre-swizzled so LDS dest stays linear (tid*16B).
  const int srow = tid >> 2;
  const int sq = tid & 3;
  const int gs0 = ((sq ^ (srow & 3)) * 8);
  const long long gaA0 = (long long)(m0 + srow) * lda + gs0;
  const long long gaA1 = (long long)(m0 + srow + 64) * lda + gs0;
  const long long gaB0 = (long long)(n0 + srow) * ldb + gs0;
  const long long gaB1 = (long long)(n0 + srow + 64) * ldb + gs0;

  auto stage = [&](int k0, int bo) {
    char* pAh = smem + bo;
    char* pAl = smem + bo + 8192;
    char* pBh = smem + bo + 16384;
    char* pBl = smem + bo + 24576;
    GLD16(Agh + gaA0 + k0, pAh + tid * 16);
    GLD16(Agh + gaA1 + k0, pAh + 4096 + tid * 16);
    GLD16(Agl + gaA0 + k0, pAl + tid * 16);
    GLD16(Agl + gaA1 + k0, pAl + 4096 + tid * 16);
    GLD16(Bgh + gaB0 + k0, pBh + tid * 16);
    GLD16(Bgh + gaB1 + k0, pBh + 4096 + tid * 16);
    GLD16(Bgl + gaB0 + k0, pBl + tid * 16);
    GLD16(Bgl + gaB1 + k0, pBl + 4096 + tid * 16);
  };

  // frag read offsets (swizzled slot = kg ^ (row&3)), f16 elements
  const int rl = lane & 15, kg = lane >> 4;
  int aoff[4], boff[4];
#pragma unroll
  for (int i = 0; i < 4; ++i) {
    int rowa = wrow + i * 16 + rl;
    aoff[i] = rowa * 32 + ((kg ^ (rowa & 3)) * 8);
    int rowb = wcol + i * 16 + rl;
    boff[i] = rowb * 32 + ((kg ^ (rowb & 3)) * 8);
  }

  const int nt = Kd >> 5;
  int bufo = 0;
  stage(0, 0);
  __syncthreads();
  for (int t = 0; t < nt; ++t) {
    const int nb = bufo ^ 32768;
    if (t + 1 < nt) stage((t + 1) * 32, nb);   // prefetch overlaps compute

    const f16* sAh = (const f16*)(smem + bufo);
    const f16* sAl = (const f16*)(smem + bufo + 8192);
    const f16* sBh = (const f16*)(smem + bufo + 16384);
    const f16* sBl = (const f16*)(smem + bufo + 24576);
    f16x8 fah[4], fal[4], fbh[4], fbl[4];
#pragma unroll
    for (int i = 0; i < 4; ++i) {
      fah[i] = *(const f16x8*)&sAh[aoff[i]];
      fal[i] = *(const f16x8*)&sAl[aoff[i]];
      fbh[i] = *(const f16x8*)&sBh[boff[i]];
      fbl[i] = *(const f16x8*)&sBl[boff[i]];
    }
#pragma unroll
    for (int i = 0; i < 4; ++i)
#pragma unroll
      for (int j = 0; j < 4; ++j) {
        acc[i][j] = __builtin_amdgcn_mfma_f32_16x16x32_f16(fah[i], fbh[j], acc[i][j], 0, 0, 0);
        acc[i][j] = __builtin_amdgcn_mfma_f32_16x16x32_f16(fah[i], fbl[j], acc[i][j], 0, 0, 0);
        acc[i][j] = __builtin_amdgcn_mfma_f32_16x16x32_f16(fal[i], fbh[j], acc[i][j], 0, 0, 0);
      }
    __syncthreads();   // vmcnt(0) drain = prefetch landed; buffers swap safely
    bufo = nb;
  }

  // C/D layout (measured, m89): col = lane&15, row = (lane>>4)*4 + reg
  if (EPI <= 1) {
    // pack hi/lo f16 planes into registers once
    f16x4 ph[4][4], pl[4][4];
#pragma unroll
    for (int i = 0; i < 4; ++i)
#pragma unroll
      for (int j = 0; j < 4; ++j)
#pragma unroll
        for (int q = 0; q < 4; ++q) {
          float v = (EPI == 1) ? fast_tanh(acc[i][j][q]) : acc[i][j][q];
          f16 h, l; fsplit(v, h, l);
          ph[i][j][q] = h; pl[i][j][q] = l;
        }
    f16* img = (f16*)smem;            // [128][136] padded image
    const int q4 = lane >> 4, c16 = lane & 15;
    const int nplanes = (EPI == 1) ? 4 : 2;
#pragma unroll
    for (int plane = 0; plane < 4; ++plane) {
      if (plane >= nplanes) break;
      const int lo = plane & 1, tr = plane >> 1;
      __syncthreads();                // image free (previous reads done)
      if (!tr) {                      // [row=t][col=n]
#pragma unroll
        for (int i = 0; i < 4; ++i)
#pragma unroll
          for (int j = 0; j < 4; ++j)
#pragma unroll
            for (int q = 0; q < 4; ++q)
              img[(wrow + i * 16 + kg * 4 + q) * 136 + wcol + j * 16 + rl] =
                  lo ? pl[i][j][q] : ph[i][j][q];
      } else {                        // transposed image [row=n][col=t]
#pragma unroll
        for (int i = 0; i < 4; ++i)
#pragma unroll
          for (int j = 0; j < 4; ++j)
            *(f16x4*)&img[(wcol + j * 16 + rl) * 136 + wrow + i * 16 + kg * 4] =
                lo ? pl[i][j] : ph[i][j];
      }
      __syncthreads();
      f16* gb; int grow0, gcol0, ldg;
      if (!tr) { gb = (lo ? g.Cl : g.Ch) + (long long)b * g.sC; grow0 = m0; gcol0 = n0; ldg = g.ldc; }
      else     { gb = (lo ? g.Tl : g.Th) + (long long)b * g.sT; grow0 = n0; gcol0 = m0; ldg = g.ldt; }
#pragma unroll
      for (int it = 0; it < 8; ++it) {
        int r = it * 16 + wid * 4 + q4;
        *(f16x8*)&gb[(long long)(grow0 + r) * ldg + gcol0 + c16 * 8] =
            *(const f16x8*)&img[r * 136 + c16 * 8];
      }
    }
  } else {
    const f16* bh = g.Ch + (long long)b * g.sC;
    const f16* bl = g.Cl + (long long)b * g.sC;
    const int ldc = g.ldc;
    float zp[4] = {0.f, 0.f, 0.f, 0.f};
#pragma unroll
    for (int i = 0; i < 4; ++i)
#pragma unroll
      for (int q = 0; q < 4; ++q) {
        int grow = m0 + wrow + i * 16 + kg * 4 + q;
        float wv = g.wh[grow];
#pragma unroll
        for (int j = 0; j < 4; ++j) {
          int gcol = n0 + wcol + j * 16 + rl;
          long long bi = (long long)grow * ldc + gcol;
          float bias = (float)bh[bi] + (float)bl[bi];
          zp[j] += wv * fast_tanh(acc[i][j][q] + bias);
        }
      }
#pragma unroll
    for (int j = 0; j < 4; ++j) {  // reduce the 4 kg-lanes sharing a column
      zp[j] += __shfl_xor(zp[j], 16);
      zp[j] += __shfl_xor(zp[j], 32);
    }
    __syncthreads();
    float* zred = (float*)smem;
    if (lane < 16) {
#pragma unroll
      for (int j = 0; j < 4; ++j)
        zred[(wid >> 1) * 128 + wcol + j * 16 + lane] = zp[j];
    }
    __syncthreads();
    if (tid < 128)
      g.z[(long long)b * 512 + n0 + tid] = zred[tid] + zred[128 + tid];
  }
}

// ---------------------------------------------------------------------------
__global__ void cvt_hilo2(const float* __restrict__ s0, f16* __restrict__ h0,
                          f16* __restrict__ l0_,
                          const float* __restrict__ s1, f16* __restrict__ h1,
                          f16* __restrict__ l1_, int n4)
{
  const float* src = blockIdx.y ? s1 : s0;
  f16* hi = blockIdx.y ? h1 : h0;
  f16* lo = blockIdx.y ? l1_ : l0_;
  int stride = gridDim.x * blockDim.x;
  for (int i = blockIdx.x * blockDim.x + threadIdx.x; i < n4; i += stride) {
    f32x4 v = ((const f32x4*)src)[i];
    f16x4 h, l;
#pragma unroll
    for (int c = 0; c < 4; ++c) {
      f16 hh, ll;
      fsplit(v[c], hh, ll);
      h[c] = hh; l[c] = ll;
    }
    ((f16x4*)hi)[i] = h;
    ((f16x4*)lo)[i] = l;
  }
}

__global__ void prep_weights(const float* __restrict__ Wl, const float* __restrict__ Ws,
                             const float* __restrict__ Wc, const float* __restrict__ whs,
                             const float* __restrict__ whc,
                             f16* __restrict__ WlT_hi, f16* __restrict__ WlT_lo,
                             f16* __restrict__ Ws2_hi, f16* __restrict__ Ws2_lo,
                             f16* __restrict__ Wc2_hi, f16* __restrict__ Wc2_lo,
                             float* __restrict__ whs2, float* __restrict__ whc2)
{
  const int blk = blockIdx.x, t = threadIdx.x;
  if (blk < 256) {            // WlT[D][d] = Wl[d][D]
    f16 h, l;
    fsplit(Wl[t * 256 + blk], h, l);
    WlT_hi[blk * 256 + t] = h;
    WlT_lo[blk * 256 + t] = l;
  } else if (blk < 384) {     // Ws padded K 80->128
    int k = blk - 256;
    f16 h, l;
    fsplit((k < 80) ? Ws[k * 256 + t] : 0.f, h, l);
    Ws2_hi[k * 256 + t] = h;
    Ws2_lo[k * 256 + t] = l;
  } else if (blk < 512) {     // Wc padded
    int k = blk - 384;
    f16 h, l;
    fsplit((k < 80) ? Wc[k * 256 + t] : 0.f, h, l);
    Wc2_hi[k * 256 + t] = h;
    Wc2_lo[k * 256 + t] = l;
  } else {
    if (t < 128) whs2[t] = (t < 80) ? whs[t] : 0.f;
    else { int k = t - 128; whc2[k] = (k < 80) ? whc[k] : 0.f; }
  }
}

// Per-chunk softmax + pooling; X planes are the chunk's f16-hi inputs.
__global__ __launch_bounds__(256) void finalize(
    const f16* __restrict__ content_h, const f16* __restrict__ comments_h,
    const float* __restrict__ zs_c, const float* __restrict__ zc_c,
    float* __restrict__ out_c)
{
  const int b = blockIdx.x;          // local chunk batch
  const int half = blockIdx.y;
  const int tid = threadIdx.x;
  __shared__ float w[512];
  __shared__ float red[256];
  const float* z = (half ? zc_c : zs_c) + b * 512;
  const f16* X = (half ? comments_h : content_h) + (long long)b * 512 * 256;
  float v0 = z[tid], v1 = z[tid + 256];
  red[tid] = fmaxf(v0, v1);
  __syncthreads();
  for (int s = 128; s > 0; s >>= 1) {
    if (tid < s) red[tid] = fmaxf(red[tid], red[tid + s]);
    __syncthreads();
  }
  float mx = red[0];
  __syncthreads();
  float e0 = __expf(v0 - mx), e1 = __expf(v1 - mx);
  red[tid] = e0 + e1;
  __syncthreads();
  for (int s = 128; s > 0; s >>= 1) {
    if (tid < s) red[tid] += red[tid + s];
    __syncthreads();
  }
  float inv = 1.0f / red[0];
  w[tid] = e0 * inv;
  w[tid + 256] = e1 * inv;
  __syncthreads();
  float acc2 = 0.f;
  for (int r = 0; r < 512; ++r)
    acc2 = fmaf(w[r], (float)X[(long long)r * 256 + tid], acc2);
  out_c[(long long)b * 512 + half * 256 + tid] = acc2;
}

// ---------------------------------------------------------------------------
extern "C" void kernel_launch(void* const* d_in, const int* in_sizes, int n_in,
                              void* d_out, int out_size, void* d_ws, size_t ws_size,
                              hipStream_t stream) {
  (void)in_sizes; (void)n_in; (void)out_size;
  const float* content  = (const float*)d_in[0];
  const float* comments = (const float*)d_in[1];
  const float* Wl  = (const float*)d_in[2];
  const float* Wc  = (const float*)d_in[3];
  const float* Ws  = (const float*)d_in[4];
  const float* whs = (const float*)d_in[5];
  const float* whc = (const float*)d_in[6];
  float* out = (float*)d_out;

  const long long PBcm = 512 * 256;   // per-batch elems, content/comments
  const long long PBL  = 512 * 512;   // per-batch elems, L / LT
  const long long PBsc = 128 * 512;   // per-batch elems, Sc / Cc

  // per-batch chunked ws: c/m 4 planes (1 MiB) + CW(=Sc/Cc alias) 0.5 MiB
  //                       + L 1 MiB + LT 1 MiB = 3.5 MiB; fixed ~1.2 MiB.
  const size_t perG = 3670016;   // 3.5 MiB
  int G = 16;
  if      (ws_size >= 64 * perG + (4ULL << 20)) G = 64;
  else if (ws_size >= 32 * perG + (4ULL << 20)) G = 32;

  char* base = (char*)d_ws;
  size_t off = 0;
  auto alloc = [&](size_t bytes) -> char* {
    char* p = base + off;
    off = (off + bytes + 255) & ~(size_t)255;
    return p;
  };

  // chunked planes
  f16* c_hi  = (f16*)alloc((size_t)G * PBcm * 2);
  f16* c_lo  = (f16*)alloc((size_t)G * PBcm * 2);
  f16* m_hi  = (f16*)alloc((size_t)G * PBcm * 2);
  f16* m_lo  = (f16*)alloc((size_t)G * PBcm * 2);
  f16* CW_hi = (f16*)alloc((size_t)G * PBcm * 2);
  f16* CW_lo = (f16*)alloc((size_t)G * PBcm * 2);
  f16* L_hi  = (f16*)alloc((size_t)G * PBL * 2);
  f16* L_lo  = (f16*)alloc((size_t)G * PBL * 2);
  f16* LT_hi = (f16*)alloc((size_t)G * PBL * 2);
  f16* LT_lo = (f16*)alloc((size_t)G * PBL * 2);
  // Sc/Cc alias the CW region (CW dead after step 3; 4*G*PBsc == 2*G*PBcm)
  f16* Sc_hi = CW_hi;
  f16* Sc_lo = Sc_hi + (size_t)G * PBsc;
  f16* Cc_hi = Sc_lo + (size_t)G * PBsc;
  f16* Cc_lo = Cc_hi + (size_t)G * PBsc;
  // fixed
  f16* WlT_hi = (f16*)alloc(256 * 256 * 2);
  f16* WlT_lo = (f16*)alloc(256 * 256 * 2);
  f16* Ws2_hi = (f16*)alloc(128 * 256 * 2);
  f16* Ws2_lo = (f16*)alloc(128 * 256 * 2);
  f16* Wc2_hi = (f16*)alloc(128 * 256 * 2);
  f16* Wc2_lo = (f16*)alloc(128 * 256 * 2);
  float* whs2 = (float*)alloc(512);
  float* whc2 = (float*)alloc(512);
  float* zs = (float*)alloc(128 * 512 * 4);
  float* zc = (float*)alloc(128 * 512 * 4);

  dim3 blk(256);

  prep_weights<<<dim3(513), blk, 0, stream>>>(Wl, Ws, Wc, whs, whc,
      WlT_hi, WlT_lo, Ws2_hi, Ws2_lo, Wc2_hi, Wc2_lo, whs2, whc2);

  for (int c0 = 0; c0 < 128; c0 += G) {
    // 1. convert this chunk's inputs to hi/lo f16
    cvt_hilo2<<<dim3(1024, 2), blk, 0, stream>>>(
        content + (long long)c0 * PBcm, c_hi, c_lo,
        comments + (long long)c0 * PBcm, m_hi, m_lo,
        (int)((long long)G * PBcm / 4));

    GemmArgs a, b2;

    // 2. CW = comments @ Wl   (M=512, N=256, K=256)
    a = {m_hi, m_lo, 256, PBcm,  WlT_hi, WlT_lo, 256, 0,
         CW_hi, CW_lo, 256, PBcm,  nullptr, nullptr, 0, 0,  nullptr, nullptr};
    mgemm<0, 1><<<dim3(2, 4, G), blk, 0, stream>>>(a, a, 256);

    // 3. L = tanh(CW @ content^T) -> L[t][n] + LT[n][t], hi/lo
    a = {CW_hi, CW_lo, 256, PBcm,  c_hi, c_lo, 256, PBcm,
         L_hi, L_lo, 512, PBL,  LT_hi, LT_lo, 512, PBL,  nullptr, nullptr};
    mgemm<1, 1><<<dim3(4, 4, G), blk, 0, stream>>>(a, a, 256);

    // 4+5. Sc = Ws2 @ content^T ; Cc = Wc2 @ comments^T  (merged via y;
    //      writes alias the dead CW region)
    a  = {Ws2_hi, Ws2_lo, 256, 0,  c_hi, c_lo, 256, PBcm,
          Sc_hi, Sc_lo, 512, PBsc,  nullptr, nullptr, 0, 0,  nullptr, nullptr};
    b2 = {Wc2_hi, Wc2_lo, 256, 0,  m_hi, m_lo, 256, PBcm,
          Cc_hi, Cc_lo, 512, PBsc,  nullptr, nullptr, 0, 0,  nullptr, nullptr};
    mgemm<0, 2><<<dim3(4, 2, G), blk, 0, stream>>>(a, b2, 256);

    // 6+7. zs[n] = sum_k whs[k] tanh(Sc[k,n] + Cc@LT) ;
    //      zc[t] = sum_k whc[k] tanh(Cc[k,t] + Sc@L)   (merged via y, K=512)
    a  = {Cc_hi, Cc_lo, 512, PBsc,  LT_hi, LT_lo, 512, PBL,
          Sc_hi, Sc_lo, 512, PBsc,  nullptr, nullptr, 0, 0,
          whs2, zs + (long long)c0 * 512};
    b2 = {Sc_hi, Sc_lo, 512, PBsc,  L_hi, L_lo, 512, PBL,
          Cc_hi, Cc_lo, 512, PBsc,  nullptr, nullptr, 0, 0,
          whc2, zc + (long long)c0 * 512};
    mgemm<2, 2><<<dim3(4, 2, G), blk, 0, stream>>>(a, b2, 512);

    // 8. per-chunk softmax + pooling, reading the chunk's f16-hi planes
    //    (still live; overwritten only by the next chunk's cvt)
    finalize<<<dim3(G, 2), blk, 0, stream>>>(
        c_hi, m_hi, zs + (long long)c0 * 512, zc + (long long)c0 * 512,
        out + (long long)c0 * 512);
  }
}